// Round 3
// baseline (1107.547 us; speedup 1.0000x reference)
//
#include <hip/hip_runtime.h>
#include <cstdint>
#include <cstddef>

#define N_NODESC 50000
#define N_EDGESC 600000
#define N_GRAPHSC 64
#define D_HIDC   128
#define D_LATC   64
#define D_CATC   1664    // 13*128

#define CHUNK_N  16704   // 261 * 64 nodes per chunk
#define N_CHUNKS 3
#define H_ROWS   50112   // 3 * 16704

typedef unsigned short u16;
typedef unsigned int   u32;

typedef __bf16 bf16x8 __attribute__((ext_vector_type(8)));
typedef float  f32x4  __attribute__((ext_vector_type(4)));

__device__ __forceinline__ u16 f2bf(float f) {
    u32 u = __builtin_bit_cast(u32, f);
    u += 0x7fffu + ((u >> 16) & 1u);   // round-to-nearest-even
    return (u16)(u >> 16);
}
__device__ __forceinline__ float bf2f(u16 h) {
    u32 u = ((u32)h) << 16;
    return __builtin_bit_cast(float, u);
}

// ---------------- setup kernels ----------------

__global__ void k_zero(int* p, int n) {
    int i = blockIdx.x * 256 + threadIdx.x;
    if (i < n) p[i] = 0;
}

__global__ void k_count(const int* __restrict__ dst, int* __restrict__ deg) {
    int e = blockIdx.x * 256 + threadIdx.x;
    if (e < N_EDGESC) atomicAdd(&deg[dst[e]], 1);
}

__global__ void k_scan_part(const int* __restrict__ deg, int* __restrict__ bsum) {
    __shared__ int s[256];
    int idx = blockIdx.x * 256 + threadIdx.x;
    int v = (idx < N_NODESC) ? deg[idx] : 0;
    s[threadIdx.x] = v; __syncthreads();
    for (int o = 128; o > 0; o >>= 1) {
        if (threadIdx.x < o) s[threadIdx.x] += s[threadIdx.x + o];
        __syncthreads();
    }
    if (threadIdx.x == 0) bsum[blockIdx.x] = s[0];
}

__global__ void k_scan_block(int* bsum) {
    __shared__ int s[256];
    int t = threadIdx.x;
    int v = bsum[t];
    s[t] = v; __syncthreads();
    for (int o = 1; o < 256; o <<= 1) {
        int add = (t >= o) ? s[t - o] : 0;
        __syncthreads();
        s[t] += add;
        __syncthreads();
    }
    bsum[t] = s[t] - v;   // exclusive
}

__global__ void k_scan_final(const int* __restrict__ deg, const int* __restrict__ bsum,
                             int* __restrict__ row_off) {
    __shared__ int s[256];
    int t = threadIdx.x;
    int idx = blockIdx.x * 256 + t;
    int v = (idx < N_NODESC) ? deg[idx] : 0;
    s[t] = v; __syncthreads();
    for (int o = 1; o < 256; o <<= 1) {
        int add = (t >= o) ? s[t - o] : 0;
        __syncthreads();
        s[t] += add;
        __syncthreads();
    }
    int excl = s[t] - v + bsum[blockIdx.x];
    if (idx < N_NODESC) row_off[idx] = excl;
    if (idx == 0) row_off[N_NODESC] = N_EDGESC;
}

__global__ void k_logsum(const int* __restrict__ deg, float* dsum) {
    __shared__ float s[256];
    int idx = blockIdx.x * 256 + threadIdx.x;
    float v = (idx < N_NODESC) ? logf((float)deg[idx] + 1.0f) : 0.0f;
    s[threadIdx.x] = v; __syncthreads();
    for (int o = 128; o > 0; o >>= 1) {
        if (threadIdx.x < o) s[threadIdx.x] += s[threadIdx.x + o];
        __syncthreads();
    }
    if (threadIdx.x == 0) atomicAdd(dsum, s[0]);
}

__global__ void k_fill_csr(const int* __restrict__ src, const int* __restrict__ dst,
                           const int* __restrict__ row_off, int* __restrict__ cursor,
                           int* __restrict__ csr_src) {
    int e = blockIdx.x * 256 + threadIdx.x;
    if (e < N_EDGESC) {
        int d = dst[e];
        int pos = row_off[d] + atomicAdd(&cursor[d], 1);
        csr_src[pos] = src[e];
    }
}

__global__ void k_amp_att(const int* __restrict__ deg, const float* __restrict__ dsum,
                          float* __restrict__ amp, float* __restrict__ att) {
    int n = blockIdx.x * 256 + threadIdx.x;
    if (n < N_NODESC) {
        float delta = dsum[0] * (1.0f / (float)N_NODESC);
        float logd = logf((float)deg[n] + 1.0f);
        amp[n] = logd / delta;
        att[n] = delta / fmaxf(logd, 1e-5f);
    }
}

// transpose [1664][128] fp32 -> hi/lo bf16 [128][1664]
__global__ void k_wconv(const float* __restrict__ W, u16* __restrict__ Whi,
                        u16* __restrict__ Wlo) {
    int i = blockIdx.x * 256 + threadIdx.x;
    if (i < D_CATC * D_HIDC) {
        int k = i / D_HIDC, j = i % D_HIDC;
        float w = W[i];
        u16 hi = f2bf(w);
        u16 lo = f2bf(w - bf2f(hi));
        Whi[(size_t)j * D_CATC + k] = hi;
        Wlo[(size_t)j * D_CATC + k] = lo;
    }
}

// ---------------- per-layer kernels ----------------

// one wave per node; lane owns feature columns 2*lane, 2*lane+1
// writes hi/lo bf16 split feat for chunk-local rows
__global__ void __launch_bounds__(256) k_aggregate(
        const float* __restrict__ h, const int* __restrict__ row_off,
        const int* __restrict__ csr_src,
        const float* __restrict__ amp, const float* __restrict__ att,
        u16* __restrict__ fh, u16* __restrict__ fl, int chunk0) {
    int wl = blockIdx.x * 4 + (threadIdx.x >> 6);
    if (wl >= CHUNK_N) return;
    int n = chunk0 + wl;
    if (n >= N_NODESC) return;
    int lane = threadIdx.x & 63;
    int beg = row_off[n], end = row_off[n + 1];
    float s0 = 0.f, s1 = 0.f, q0 = 0.f, q1 = 0.f;
    float mx0 = -3.4e38f, mx1 = -3.4e38f, mn0 = 3.4e38f, mn1 = 3.4e38f;
    for (int i = beg; i < end; i++) {
        int src = csr_src[i];
        float2 v = *(const float2*)(h + (size_t)src * D_HIDC + 2 * lane);
        s0 += v.x; s1 += v.y;
        q0 += v.x * v.x; q1 += v.y * v.y;
        mx0 = fmaxf(mx0, v.x); mx1 = fmaxf(mx1, v.y);
        mn0 = fminf(mn0, v.x); mn1 = fminf(mn1, v.y);
    }
    int d = end - beg;
    float inv = 1.0f / fmaxf((float)d, 1.0f);
    float mean0 = s0 * inv, mean1 = s1 * inv;
    float std0 = sqrtf(fmaxf(q0 * inv - mean0 * mean0, 0.0f) + 1e-5f);
    float std1 = sqrtf(fmaxf(q1 * inv - mean1 * mean1, 0.0f) + 1e-5f);
    if (d == 0) { mx0 = mx1 = mn0 = mn1 = 0.0f; }
    float a_ = amp[n], t_ = att[n];
    size_t rb = (size_t)wl * D_CATC;
    u32 c = 2 * lane;
    auto st = [&](int off, float A, float B) {
        u16 ah = f2bf(A); u16 al = f2bf(A - bf2f(ah));
        u16 bh = f2bf(B); u16 bl = f2bf(B - bf2f(bh));
        *(u32*)(fh + rb + off + c) = (u32)ah | ((u32)bh << 16);
        *(u32*)(fl + rb + off + c) = (u32)al | ((u32)bl << 16);
    };
    float2 hv = *(const float2*)(h + (size_t)n * D_HIDC + c);
    st(0, hv.x, hv.y);
    st(128,  mean0, mean1);
    st(256,  mx0, mx1);
    st(384,  mn0, mn1);
    st(512,  std0, std1);
    st(640,  mean0 * a_, mean1 * a_);
    st(768,  mx0 * a_, mx1 * a_);
    st(896,  mn0 * a_, mn1 * a_);
    st(1024, std0 * a_, std1 * a_);
    st(1152, mean0 * t_, mean1 * t_);
    st(1280, mx0 * t_, mx1 * t_);
    st(1408, mn0 * t_, mn1 * t_);
    st(1536, std0 * t_, std1 * t_);
}

// h_out[node][j] = relu(bias[j] + sum_k feat[node][k] * W[k][j]) via split bf16:
// D = Ahi*Bhi + Ahi*Blo + Alo*Bhi   (A = Wt [j][k], B = feat [n][k])
__global__ void __launch_bounds__(256) k_gemm(
        const u16* __restrict__ fh, const u16* __restrict__ fl,
        const u16* __restrict__ wh, const u16* __restrict__ wl,
        const float* __restrict__ bias, float* __restrict__ hout, int chunk0) {
    __shared__ u16 Ah[128 * 32];   // 8 KB
    __shared__ u16 Al[128 * 32];   // 8 KB
    __shared__ u16 Bh[64 * 32];    // 4 KB
    __shared__ u16 Bl[64 * 32];    // 4 KB
    int n0 = blockIdx.x * 64;      // chunk-local
    int t = threadIdx.x;
    int w = t >> 6, lane = t & 63;
    f32x4 acc[2][4];
    #pragma unroll
    for (int a = 0; a < 2; a++)
        #pragma unroll
        for (int b = 0; b < 4; b++) acc[a][b] = (f32x4){0.f, 0.f, 0.f, 0.f};

    for (int k0 = 0; k0 < D_CATC; k0 += 32) {
        __syncthreads();
        {   // stage A hi+lo: 512 16B chunks each, 2 per thread
            int c = t;
            int row = c >> 2, off = (c & 3) * 8;
            size_t g = (size_t)row * D_CATC + k0 + off;
            *(uint4*)&Ah[row * 32 + off] = *(const uint4*)&wh[g];
            *(uint4*)&Al[row * 32 + off] = *(const uint4*)&wl[g];
            c = t + 256; row = c >> 2; off = (c & 3) * 8;
            g = (size_t)row * D_CATC + k0 + off;
            *(uint4*)&Ah[row * 32 + off] = *(const uint4*)&wh[g];
            *(uint4*)&Al[row * 32 + off] = *(const uint4*)&wl[g];
        }
        {   // stage B hi+lo: 256 16B chunks each, 1 per thread
            int row = t >> 2, off = (t & 3) * 8;
            size_t g = (size_t)(n0 + row) * D_CATC + k0 + off;
            *(uint4*)&Bh[row * 32 + off] = *(const uint4*)&fh[g];
            *(uint4*)&Bl[row * 32 + off] = *(const uint4*)&fl[g];
        }
        __syncthreads();
        int q8 = (lane >> 4) * 8;
        int r = lane & 15;
        bf16x8 a0h = *(const bf16x8*)&Ah[(w * 32 + r) * 32 + q8];
        bf16x8 a1h = *(const bf16x8*)&Ah[(w * 32 + 16 + r) * 32 + q8];
        bf16x8 a0l = *(const bf16x8*)&Al[(w * 32 + r) * 32 + q8];
        bf16x8 a1l = *(const bf16x8*)&Al[(w * 32 + 16 + r) * 32 + q8];
        #pragma unroll
        for (int nt = 0; nt < 4; nt++) {
            bf16x8 bh = *(const bf16x8*)&Bh[(nt * 16 + r) * 32 + q8];
            bf16x8 bl = *(const bf16x8*)&Bl[(nt * 16 + r) * 32 + q8];
            acc[0][nt] = __builtin_amdgcn_mfma_f32_16x16x32_bf16(a0h, bh, acc[0][nt], 0, 0, 0);
            acc[0][nt] = __builtin_amdgcn_mfma_f32_16x16x32_bf16(a0h, bl, acc[0][nt], 0, 0, 0);
            acc[0][nt] = __builtin_amdgcn_mfma_f32_16x16x32_bf16(a0l, bh, acc[0][nt], 0, 0, 0);
            acc[1][nt] = __builtin_amdgcn_mfma_f32_16x16x32_bf16(a1h, bh, acc[1][nt], 0, 0, 0);
            acc[1][nt] = __builtin_amdgcn_mfma_f32_16x16x32_bf16(a1h, bl, acc[1][nt], 0, 0, 0);
            acc[1][nt] = __builtin_amdgcn_mfma_f32_16x16x32_bf16(a1l, bh, acc[1][nt], 0, 0, 0);
        }
    }
    // D[row=(lane>>4)*4+r][col=lane&15]; row -> j, col -> node
    int col = lane & 15;
    int rowq = (lane >> 4) * 4;
    #pragma unroll
    for (int mt = 0; mt < 2; mt++) {
        int jb = w * 32 + mt * 16 + rowq;
        float b0 = bias[jb], b1 = bias[jb + 1], b2 = bias[jb + 2], b3 = bias[jb + 3];
        #pragma unroll
        for (int nt = 0; nt < 4; nt++) {
            int node = chunk0 + n0 + nt * 16 + col;
            f32x4 v = acc[mt][nt];
            float4 o;
            o.x = fmaxf(v.x + b0, 0.0f);
            o.y = fmaxf(v.y + b1, 0.0f);
            o.z = fmaxf(v.z + b2, 0.0f);
            o.w = fmaxf(v.w + b3, 0.0f);
            *(float4*)&hout[(size_t)node * D_HIDC + jb] = o;
        }
    }
}

// ---------------- epilogue kernels ----------------

__global__ void k_pool(const float* __restrict__ h, const int* __restrict__ batch,
                       float* __restrict__ pooled) {
    int j = threadIdx.x;   // 128 threads
    int n0 = blockIdx.x * 128;
    int nend = min(n0 + 128, N_NODESC);
    float accum = 0.0f;
    int curg = batch[n0];
    for (int n = n0; n < nend; n++) {
        int g = batch[n];
        if (g != curg) {
            atomicAdd(&pooled[curg * D_HIDC + j], accum);
            accum = 0.0f; curg = g;
        }
        accum += h[(size_t)n * D_HIDC + j];
    }
    atomicAdd(&pooled[curg * D_HIDC + j], accum);
}

__global__ void __launch_bounds__(256) k_bn_fc(
        const float* __restrict__ pooled, const float* __restrict__ gamma,
        const float* __restrict__ beta, const float* __restrict__ fcW,
        const float* __restrict__ fcb, float* __restrict__ out) {
    __shared__ float bn[N_GRAPHSC * D_HIDC];   // 32 KB
    int t = threadIdx.x;
    if (t < D_HIDC) {
        float s = 0.f, q = 0.f;
        for (int g = 0; g < N_GRAPHSC; g++) {
            float v = pooled[g * D_HIDC + t];
            s += v; q += v * v;
        }
        float mu = s * (1.0f / N_GRAPHSC);
        float var = q * (1.0f / N_GRAPHSC) - mu * mu;
        float inv = 1.0f / sqrtf(var + 1e-5f);
        float ga = gamma[t], be = beta[t];
        for (int g = 0; g < N_GRAPHSC; g++)
            bn[g * D_HIDC + t] = (pooled[g * D_HIDC + t] - mu) * inv * ga + be;
    }
    __syncthreads();
    for (int o = t; o < N_GRAPHSC * D_LATC; o += 256) {
        int g = o / D_LATC, l = o % D_LATC;
        float accum = fcb[l];
        for (int j = 0; j < D_HIDC; j++) accum += bn[g * D_HIDC + j] * fcW[j * D_LATC + l];
        out[o] = accum;
    }
}

// ---------------- launch ----------------

extern "C" void kernel_launch(void* const* d_in, const int* in_sizes, int n_in,
                              void* d_out, int out_size, void* d_ws, size_t ws_size,
                              hipStream_t stream) {
    const float* x     = (const float*)d_in[0];
    const int*   ei    = (const int*)d_in[1];
    const int*   batch = (const int*)d_in[2];
    const float* W0 = (const float*)d_in[3];
    const float* b0 = (const float*)d_in[4];
    const float* W1 = (const float*)d_in[5];
    const float* b1 = (const float*)d_in[6];
    const float* W2 = (const float*)d_in[7];
    const float* b2 = (const float*)d_in[8];
    const float* gamma = (const float*)d_in[9];
    const float* beta  = (const float*)d_in[10];
    const float* fcW   = (const float*)d_in[11];
    const float* fcb   = (const float*)d_in[12];
    float* out = (float*)d_out;
    const int* srcv = ei;
    const int* dstv = ei + N_EDGESC;

    char* p = (char*)d_ws;
    auto alloc = [&](size_t bytes) -> char* {
        char* r = p;
        p += (bytes + 255) & ~(size_t)255;
        return r;
    };
    int*   deg_cnt = (int*)alloc((size_t)N_NODESC * 4);
    int*   cursor  = (int*)alloc((size_t)N_NODESC * 4);
    int*   bsum    = (int*)alloc(256 * 4);
    float* dsum    = (float*)alloc(4);
    float* pooled  = (float*)alloc((size_t)N_GRAPHSC * D_HIDC * 4);
    char*  zero_end = p;
    int*   row_off = (int*)alloc((size_t)(N_NODESC + 1) * 4);
    int*   csr_src = (int*)alloc((size_t)N_EDGESC * 4);
    float* amp     = (float*)alloc((size_t)N_NODESC * 4);
    float* att     = (float*)alloc((size_t)N_NODESC * 4);
    u16*   Wt_hi   = (u16*)alloc((size_t)3 * D_CATC * D_HIDC * 2);
    u16*   Wt_lo   = (u16*)alloc((size_t)3 * D_CATC * D_HIDC * 2);
    float* hA      = (float*)alloc((size_t)H_ROWS * D_HIDC * 4);
    float* hB      = (float*)alloc((size_t)H_ROWS * D_HIDC * 4);
    u16*   feat_hi = (u16*)alloc((size_t)CHUNK_N * D_CATC * 2);
    u16*   feat_lo = (u16*)alloc((size_t)CHUNK_N * D_CATC * 2);

    int nz = (int)((zero_end - (char*)deg_cnt) / 4);
    k_zero<<<(nz + 255) / 256, 256, 0, stream>>>(deg_cnt, nz);
    k_count<<<(N_EDGESC + 255) / 256, 256, 0, stream>>>(dstv, deg_cnt);
    k_scan_part<<<196, 256, 0, stream>>>(deg_cnt, bsum);
    k_scan_block<<<1, 256, 0, stream>>>(bsum);
    k_scan_final<<<196, 256, 0, stream>>>(deg_cnt, bsum, row_off);
    k_logsum<<<196, 256, 0, stream>>>(deg_cnt, dsum);
    k_fill_csr<<<(N_EDGESC + 255) / 256, 256, 0, stream>>>(srcv, dstv, row_off, cursor, csr_src);
    k_amp_att<<<196, 256, 0, stream>>>(deg_cnt, dsum, amp, att);
    int wgrid = (D_CATC * D_HIDC + 255) / 256;
    size_t wsz = (size_t)D_CATC * D_HIDC;
    k_wconv<<<wgrid, 256, 0, stream>>>(W0, Wt_hi,           Wt_lo);
    k_wconv<<<wgrid, 256, 0, stream>>>(W1, Wt_hi + wsz,     Wt_lo + wsz);
    k_wconv<<<wgrid, 256, 0, stream>>>(W2, Wt_hi + 2 * wsz, Wt_lo + 2 * wsz);

    const float* bs[3] = {b0, b1, b2};
    const float* h_in[3]  = {x,  hA, hB};
    float*       h_out[3] = {hA, hB, hA};
    for (int l = 0; l < 3; l++) {
        for (int ch = 0; ch < N_CHUNKS; ch++) {
            int chunk0 = ch * CHUNK_N;
            k_aggregate<<<(CHUNK_N + 3) / 4, 256, 0, stream>>>(
                h_in[l], row_off, csr_src, amp, att, feat_hi, feat_lo, chunk0);
            k_gemm<<<CHUNK_N / 64, 256, 0, stream>>>(
                feat_hi, feat_lo, Wt_hi + (size_t)l * wsz, Wt_lo + (size_t)l * wsz,
                bs[l], h_out[l], chunk0);
        }
    }
    k_pool<<<(N_NODESC + 127) / 128, 128, 0, stream>>>(h_out[2], batch, pooled);
    k_bn_fc<<<1, 256, 0, stream>>>(pooled, gamma, beta, fcW, fcb, out);
}

// Round 4
// 838.707 us; speedup vs baseline: 1.3205x; 1.3205x over previous
//
#include <hip/hip_runtime.h>
#include <cstdint>
#include <cstddef>

#define N_NODESC 50000
#define N_EDGESC 600000
#define N_GRAPHSC 64
#define D_HIDC   128
#define D_LATC   64
#define D_CATC   1664    // 13*128

#define CHUNK_N  16704   // 261 * 64 nodes per chunk
#define N_CHUNKS 3
#define H_ROWS   50112   // 3 * 16704
#define KSLICES  4
#define KSL      416     // 1664/4 = 13 iters of 32

typedef unsigned short u16;
typedef unsigned int   u32;

typedef _Float16 f16x8 __attribute__((ext_vector_type(8)));
typedef float    f32x4 __attribute__((ext_vector_type(4)));

__device__ __forceinline__ void gll16(void* lds, const void* g) {
    // async global->LDS, 16B per lane; HW dest = wave-uniform base + lane*16
    __builtin_amdgcn_global_load_lds(
        (const __attribute__((address_space(1))) void*)g,
        (__attribute__((address_space(3))) void*)lds, 16, 0, 0);
}

// ---------------- setup kernels ----------------

__global__ void k_zero(int* p, int n) {
    int i = blockIdx.x * 256 + threadIdx.x;
    if (i < n) p[i] = 0;
}

__global__ void k_count(const int* __restrict__ dst, int* __restrict__ deg) {
    int e = blockIdx.x * 256 + threadIdx.x;
    if (e < N_EDGESC) atomicAdd(&deg[dst[e]], 1);
}

__global__ void k_scan_part(const int* __restrict__ deg, int* __restrict__ bsum) {
    __shared__ int s[256];
    int idx = blockIdx.x * 256 + threadIdx.x;
    int v = (idx < N_NODESC) ? deg[idx] : 0;
    s[threadIdx.x] = v; __syncthreads();
    for (int o = 128; o > 0; o >>= 1) {
        if (threadIdx.x < o) s[threadIdx.x] += s[threadIdx.x + o];
        __syncthreads();
    }
    if (threadIdx.x == 0) bsum[blockIdx.x] = s[0];
}

__global__ void k_scan_block(int* bsum) {
    __shared__ int s[256];
    int t = threadIdx.x;
    int v = bsum[t];
    s[t] = v; __syncthreads();
    for (int o = 1; o < 256; o <<= 1) {
        int add = (t >= o) ? s[t - o] : 0;
        __syncthreads();
        s[t] += add;
        __syncthreads();
    }
    bsum[t] = s[t] - v;   // exclusive
}

__global__ void k_scan_final(const int* __restrict__ deg, const int* __restrict__ bsum,
                             int* __restrict__ row_off) {
    __shared__ int s[256];
    int t = threadIdx.x;
    int idx = blockIdx.x * 256 + t;
    int v = (idx < N_NODESC) ? deg[idx] : 0;
    s[t] = v; __syncthreads();
    for (int o = 1; o < 256; o <<= 1) {
        int add = (t >= o) ? s[t - o] : 0;
        __syncthreads();
        s[t] += add;
        __syncthreads();
    }
    int excl = s[t] - v + bsum[blockIdx.x];
    if (idx < N_NODESC) row_off[idx] = excl;
    if (idx == 0) row_off[N_NODESC] = N_EDGESC;
}

__global__ void k_logsum(const int* __restrict__ deg, float* dsum) {
    __shared__ float s[256];
    int idx = blockIdx.x * 256 + threadIdx.x;
    float v = (idx < N_NODESC) ? logf((float)deg[idx] + 1.0f) : 0.0f;
    s[threadIdx.x] = v; __syncthreads();
    for (int o = 128; o > 0; o >>= 1) {
        if (threadIdx.x < o) s[threadIdx.x] += s[threadIdx.x + o];
        __syncthreads();
    }
    if (threadIdx.x == 0) atomicAdd(dsum, s[0]);
}

__global__ void k_fill_csr(const int* __restrict__ src, const int* __restrict__ dst,
                           const int* __restrict__ row_off, int* __restrict__ cursor,
                           int* __restrict__ csr_src) {
    int e = blockIdx.x * 256 + threadIdx.x;
    if (e < N_EDGESC) {
        int d = dst[e];
        int pos = row_off[d] + atomicAdd(&cursor[d], 1);
        csr_src[pos] = src[e];
    }
}

__global__ void k_amp_att(const int* __restrict__ deg, const float* __restrict__ dsum,
                          float* __restrict__ amp, float* __restrict__ att) {
    int n = blockIdx.x * 256 + threadIdx.x;
    if (n < N_NODESC) {
        float delta = dsum[0] * (1.0f / (float)N_NODESC);
        float logd = logf((float)deg[n] + 1.0f);
        amp[n] = logd / delta;
        att[n] = delta / fmaxf(logd, 1e-5f);
    }
}

// transpose [1664][128] fp32 -> hi/lo fp16 [128][1664]
__global__ void k_wconv(const float* __restrict__ W, u16* __restrict__ Whi,
                        u16* __restrict__ Wlo) {
    int i = blockIdx.x * 256 + threadIdx.x;
    if (i < D_CATC * D_HIDC) {
        int k = i / D_HIDC, j = i % D_HIDC;
        float w = W[i];
        _Float16 hi = (_Float16)w;
        _Float16 lo = (_Float16)(w - (float)hi);
        Whi[(size_t)j * D_CATC + k] = __builtin_bit_cast(u16, hi);
        Wlo[(size_t)j * D_CATC + k] = __builtin_bit_cast(u16, lo);
    }
}

// ---------------- per-layer kernels ----------------

// one wave per node; lane owns feature columns 2*lane, 2*lane+1
// writes fp16 feat for chunk-local rows
__global__ void __launch_bounds__(256) k_aggregate(
        const float* __restrict__ h, const int* __restrict__ row_off,
        const int* __restrict__ csr_src,
        const float* __restrict__ amp, const float* __restrict__ att,
        u16* __restrict__ fp, int chunk0) {
    int wl = blockIdx.x * 4 + (threadIdx.x >> 6);
    if (wl >= CHUNK_N) return;
    int n = chunk0 + wl;
    if (n >= N_NODESC) return;
    int lane = threadIdx.x & 63;
    int beg = row_off[n], end = row_off[n + 1];
    float s0 = 0.f, s1 = 0.f, q0 = 0.f, q1 = 0.f;
    float mx0 = -3.4e38f, mx1 = -3.4e38f, mn0 = 3.4e38f, mn1 = 3.4e38f;
    int i = beg;
    for (; i + 1 < end; i += 2) {
        int sa = csr_src[i], sb = csr_src[i + 1];
        float2 va = *(const float2*)(h + (size_t)sa * D_HIDC + 2 * lane);
        float2 vb = *(const float2*)(h + (size_t)sb * D_HIDC + 2 * lane);
        s0 += va.x + vb.x; s1 += va.y + vb.y;
        q0 += va.x * va.x + vb.x * vb.x; q1 += va.y * va.y + vb.y * vb.y;
        mx0 = fmaxf(mx0, fmaxf(va.x, vb.x)); mx1 = fmaxf(mx1, fmaxf(va.y, vb.y));
        mn0 = fminf(mn0, fminf(va.x, vb.x)); mn1 = fminf(mn1, fminf(va.y, vb.y));
    }
    if (i < end) {
        int sa = csr_src[i];
        float2 va = *(const float2*)(h + (size_t)sa * D_HIDC + 2 * lane);
        s0 += va.x; s1 += va.y;
        q0 += va.x * va.x; q1 += va.y * va.y;
        mx0 = fmaxf(mx0, va.x); mx1 = fmaxf(mx1, va.y);
        mn0 = fminf(mn0, va.x); mn1 = fminf(mn1, va.y);
    }
    int d = end - beg;
    float inv = 1.0f / fmaxf((float)d, 1.0f);
    float mean0 = s0 * inv, mean1 = s1 * inv;
    float std0 = sqrtf(fmaxf(q0 * inv - mean0 * mean0, 0.0f) + 1e-5f);
    float std1 = sqrtf(fmaxf(q1 * inv - mean1 * mean1, 0.0f) + 1e-5f);
    if (d == 0) { mx0 = mx1 = mn0 = mn1 = 0.0f; }
    float a_ = amp[n], t_ = att[n];
    size_t rb = (size_t)wl * D_CATC;
    u32 c = 2 * lane;
    auto st = [&](int off, float A, float B) {
        u32 pa = (u32)__builtin_bit_cast(u16, (_Float16)A);
        u32 pb = (u32)__builtin_bit_cast(u16, (_Float16)B);
        *(u32*)(fp + rb + off + c) = pa | (pb << 16);
    };
    float2 hv = *(const float2*)(h + (size_t)n * D_HIDC + c);
    st(0, hv.x, hv.y);
    st(128,  mean0, mean1);
    st(256,  mx0, mx1);
    st(384,  mn0, mn1);
    st(512,  std0, std1);
    st(640,  mean0 * a_, mean1 * a_);
    st(768,  mx0 * a_, mx1 * a_);
    st(896,  mn0 * a_, mn1 * a_);
    st(1024, std0 * a_, std1 * a_);
    st(1152, mean0 * t_, mean1 * t_);
    st(1280, mx0 * t_, mx1 * t_);
    st(1408, mn0 * t_, mn1 * t_);
    st(1536, std0 * t_, std1 * t_);
}

// P[ks][node_local][j] = sum_{k in slice ks} feat[n][k] * W[k][j], via 2-term fp16:
// D = Whi*B + Wlo*B.  A = Wt [j][k] hi/lo, B = feat [n][k] fp16.
// grid (261, 4): x = n-tile (64 nodes), y = k-slice.
__global__ void __launch_bounds__(256) k_gemm(
        const u16* __restrict__ fp, const u16* __restrict__ wh,
        const u16* __restrict__ wl, float* __restrict__ P) {
    __shared__ _Float16 Ah[128 * 32];   // 8 KB
    __shared__ _Float16 Al[128 * 32];   // 8 KB
    __shared__ _Float16 Bt[64 * 32];    // 4 KB
    const _Float16* whf = (const _Float16*)wh;
    const _Float16* wlf = (const _Float16*)wl;
    const _Float16* fpf = (const _Float16*)fp;
    int n0 = blockIdx.x * 64;          // chunk-local
    int kbeg = blockIdx.y * KSL;
    int t = threadIdx.x;
    int w = t >> 6, lane = t & 63;
    f32x4 acc[2][4];
    #pragma unroll
    for (int a = 0; a < 2; a++)
        #pragma unroll
        for (int b = 0; b < 4; b++) acc[a][b] = (f32x4){0.f, 0.f, 0.f, 0.f};

    int rw4 = lane >> 2;            // 0..15 (row within 16-row group)
    int koff = (lane & 3) * 8;      // 0,8,16,24
    for (int ki = 0; ki < KSL / 32; ki++) {
        int k0 = kbeg + ki * 32;
        __syncthreads();
        #pragma unroll
        for (int r = 0; r < 2; r++) {
            int row = (r * 4 + w) * 16 + rw4;
            gll16(&Ah[(r * 4 + w) * 512], whf + (size_t)row * D_CATC + k0 + koff);
            gll16(&Al[(r * 4 + w) * 512], wlf + (size_t)row * D_CATC + k0 + koff);
        }
        gll16(&Bt[w * 512], fpf + (size_t)(n0 + w * 16 + rw4) * D_CATC + k0 + koff);
        __syncthreads();
        int q8 = (lane >> 4) * 8;
        int r16 = lane & 15;
        f16x8 a0h = *(const f16x8*)&Ah[(w * 32 + r16) * 32 + q8];
        f16x8 a1h = *(const f16x8*)&Ah[(w * 32 + 16 + r16) * 32 + q8];
        f16x8 a0l = *(const f16x8*)&Al[(w * 32 + r16) * 32 + q8];
        f16x8 a1l = *(const f16x8*)&Al[(w * 32 + 16 + r16) * 32 + q8];
        #pragma unroll
        for (int nt = 0; nt < 4; nt++) {
            f16x8 b = *(const f16x8*)&Bt[(nt * 16 + r16) * 32 + q8];
            acc[0][nt] = __builtin_amdgcn_mfma_f32_16x16x32_f16(a0h, b, acc[0][nt], 0, 0, 0);
            acc[0][nt] = __builtin_amdgcn_mfma_f32_16x16x32_f16(a0l, b, acc[0][nt], 0, 0, 0);
            acc[1][nt] = __builtin_amdgcn_mfma_f32_16x16x32_f16(a1h, b, acc[1][nt], 0, 0, 0);
            acc[1][nt] = __builtin_amdgcn_mfma_f32_16x16x32_f16(a1l, b, acc[1][nt], 0, 0, 0);
        }
    }
    // D[row=(lane>>4)*4+reg][col=lane&15]; row -> j, col -> node
    float* Ps = P + (size_t)blockIdx.y * CHUNK_N * D_HIDC;
    int col = lane & 15;
    int rowq = (lane >> 4) * 4;
    #pragma unroll
    for (int mt = 0; mt < 2; mt++) {
        int jb = w * 32 + mt * 16 + rowq;
        #pragma unroll
        for (int nt = 0; nt < 4; nt++) {
            int nl = n0 + nt * 16 + col;
            f32x4 v = acc[mt][nt];
            float4 o; o.x = v.x; o.y = v.y; o.z = v.z; o.w = v.w;
            *(float4*)&Ps[(size_t)nl * D_HIDC + jb] = o;
        }
    }
}

// h_out = relu(bias + sum of 4 K-slice partials)
__global__ void __launch_bounds__(256) k_finish(
        const float* __restrict__ P, const float* __restrict__ bias,
        float* __restrict__ hout, int chunk0) {
    int i = blockIdx.x * 256 + threadIdx.x;   // indexes float4
    if (i >= CHUNK_N * (D_HIDC / 4)) return;
    int nl = i >> 5;
    int j4 = (i & 31) * 4;
    size_t off = (size_t)nl * D_HIDC + j4;
    const size_t S = (size_t)CHUNK_N * D_HIDC;
    float4 p0 = *(const float4*)&P[off];
    float4 p1 = *(const float4*)&P[off + S];
    float4 p2 = *(const float4*)&P[off + 2 * S];
    float4 p3 = *(const float4*)&P[off + 3 * S];
    float4 b = *(const float4*)&bias[j4];
    float4 o;
    o.x = fmaxf((p0.x + p1.x) + (p2.x + p3.x) + b.x, 0.0f);
    o.y = fmaxf((p0.y + p1.y) + (p2.y + p3.y) + b.y, 0.0f);
    o.z = fmaxf((p0.z + p1.z) + (p2.z + p3.z) + b.z, 0.0f);
    o.w = fmaxf((p0.w + p1.w) + (p2.w + p3.w) + b.w, 0.0f);
    *(float4*)&hout[(size_t)(chunk0 + nl) * D_HIDC + j4] = o;
}

// ---------------- epilogue kernels ----------------

__global__ void k_pool(const float* __restrict__ h, const int* __restrict__ batch,
                       float* __restrict__ pooled) {
    int j = threadIdx.x;   // 128 threads
    int n0 = blockIdx.x * 128;
    int nend = min(n0 + 128, N_NODESC);
    float accum = 0.0f;
    int curg = batch[n0];
    for (int n = n0; n < nend; n++) {
        int g = batch[n];
        if (g != curg) {
            atomicAdd(&pooled[curg * D_HIDC + j], accum);
            accum = 0.0f; curg = g;
        }
        accum += h[(size_t)n * D_HIDC + j];
    }
    atomicAdd(&pooled[curg * D_HIDC + j], accum);
}

__global__ void __launch_bounds__(256) k_bn_fc(
        const float* __restrict__ pooled, const float* __restrict__ gamma,
        const float* __restrict__ beta, const float* __restrict__ fcW,
        const float* __restrict__ fcb, float* __restrict__ out) {
    __shared__ float bn[N_GRAPHSC * D_HIDC];   // 32 KB
    int t = threadIdx.x;
    if (t < D_HIDC) {
        float s = 0.f, q = 0.f;
        for (int g = 0; g < N_GRAPHSC; g++) {
            float v = pooled[g * D_HIDC + t];
            s += v; q += v * v;
        }
        float mu = s * (1.0f / N_GRAPHSC);
        float var = q * (1.0f / N_GRAPHSC) - mu * mu;
        float inv = 1.0f / sqrtf(var + 1e-5f);
        float ga = gamma[t], be = beta[t];
        for (int g = 0; g < N_GRAPHSC; g++)
            bn[g * D_HIDC + t] = (pooled[g * D_HIDC + t] - mu) * inv * ga + be;
    }
    __syncthreads();
    for (int o = t; o < N_GRAPHSC * D_LATC; o += 256) {
        int g = o / D_LATC, l = o % D_LATC;
        float accum = fcb[l];
        for (int j = 0; j < D_HIDC; j++) accum += bn[g * D_HIDC + j] * fcW[j * D_LATC + l];
        out[o] = accum;
    }
}

// ---------------- launch ----------------

extern "C" void kernel_launch(void* const* d_in, const int* in_sizes, int n_in,
                              void* d_out, int out_size, void* d_ws, size_t ws_size,
                              hipStream_t stream) {
    const float* x     = (const float*)d_in[0];
    const int*   ei    = (const int*)d_in[1];
    const int*   batch = (const int*)d_in[2];
    const float* W0 = (const float*)d_in[3];
    const float* b0 = (const float*)d_in[4];
    const float* W1 = (const float*)d_in[5];
    const float* b1 = (const float*)d_in[6];
    const float* W2 = (const float*)d_in[7];
    const float* b2 = (const float*)d_in[8];
    const float* gamma = (const float*)d_in[9];
    const float* beta  = (const float*)d_in[10];
    const float* fcW   = (const float*)d_in[11];
    const float* fcb   = (const float*)d_in[12];
    float* out = (float*)d_out;
    const int* srcv = ei;
    const int* dstv = ei + N_EDGESC;

    char* p = (char*)d_ws;
    auto alloc = [&](size_t bytes) -> char* {
        char* r = p;
        p += (bytes + 255) & ~(size_t)255;
        return r;
    };
    int*   deg_cnt = (int*)alloc((size_t)N_NODESC * 4);
    int*   cursor  = (int*)alloc((size_t)N_NODESC * 4);
    int*   bsum    = (int*)alloc(256 * 4);
    float* dsum    = (float*)alloc(4);
    float* pooled  = (float*)alloc((size_t)N_GRAPHSC * D_HIDC * 4);
    char*  zero_end = p;
    int*   row_off = (int*)alloc((size_t)(N_NODESC + 1) * 4);
    int*   csr_src = (int*)alloc((size_t)N_EDGESC * 4);
    float* amp     = (float*)alloc((size_t)N_NODESC * 4);
    float* att     = (float*)alloc((size_t)N_NODESC * 4);
    u16*   Wt_hi   = (u16*)alloc((size_t)3 * D_CATC * D_HIDC * 2);
    u16*   Wt_lo   = (u16*)alloc((size_t)3 * D_CATC * D_HIDC * 2);
    float* hA      = (float*)alloc((size_t)H_ROWS * D_HIDC * 4);
    float* hB      = (float*)alloc((size_t)H_ROWS * D_HIDC * 4);
    u16*   feat    = (u16*)alloc((size_t)CHUNK_N * D_CATC * 2);   // fp16, 55.6 MB
    float* Pbuf    = (float*)alloc((size_t)KSLICES * CHUNK_N * D_HIDC * 4); // 34.2 MB

    int nz = (int)((zero_end - (char*)deg_cnt) / 4);
    k_zero<<<(nz + 255) / 256, 256, 0, stream>>>(deg_cnt, nz);
    k_count<<<(N_EDGESC + 255) / 256, 256, 0, stream>>>(dstv, deg_cnt);
    k_scan_part<<<196, 256, 0, stream>>>(deg_cnt, bsum);
    k_scan_block<<<1, 256, 0, stream>>>(bsum);
    k_scan_final<<<196, 256, 0, stream>>>(deg_cnt, bsum, row_off);
    k_logsum<<<196, 256, 0, stream>>>(deg_cnt, dsum);
    k_fill_csr<<<(N_EDGESC + 255) / 256, 256, 0, stream>>>(srcv, dstv, row_off, cursor, csr_src);
    k_amp_att<<<196, 256, 0, stream>>>(deg_cnt, dsum, amp, att);
    int wgrid = (D_CATC * D_HIDC + 255) / 256;
    size_t wsz = (size_t)D_CATC * D_HIDC;
    k_wconv<<<wgrid, 256, 0, stream>>>(W0, Wt_hi,           Wt_lo);
    k_wconv<<<wgrid, 256, 0, stream>>>(W1, Wt_hi + wsz,     Wt_lo + wsz);
    k_wconv<<<wgrid, 256, 0, stream>>>(W2, Wt_hi + 2 * wsz, Wt_lo + 2 * wsz);

    const float* bs[3] = {b0, b1, b2};
    const float* h_in[3]  = {x,  hA, hB};
    float*       h_out[3] = {hA, hB, hA};
    dim3 ggrid(CHUNK_N / 64, KSLICES);
    for (int l = 0; l < 3; l++) {
        for (int ch = 0; ch < N_CHUNKS; ch++) {
            int chunk0 = ch * CHUNK_N;
            k_aggregate<<<(CHUNK_N + 3) / 4, 256, 0, stream>>>(
                h_in[l], row_off, csr_src, amp, att, feat, chunk0);
            k_gemm<<<ggrid, 256, 0, stream>>>(
                feat, Wt_hi + (size_t)l * wsz, Wt_lo + (size_t)l * wsz, Pbuf);
            k_finish<<<CHUNK_N * (D_HIDC / 4) / 256, 256, 0, stream>>>(
                Pbuf, bs[l], h_out[l], chunk0);
        }
    }
    k_pool<<<(N_NODESC + 127) / 128, 128, 0, stream>>>(h_out[2], batch, pooled);
    k_bn_fc<<<1, 256, 0, stream>>>(pooled, gamma, beta, fcW, fcb, out);
}

// Round 5
// 588.772 us; speedup vs baseline: 1.8811x; 1.4245x over previous
//
#include <hip/hip_runtime.h>
#include <cstdint>
#include <cstddef>

#define N_NODESC 50000
#define N_PAD    50048   // 782 * 64
#define N_EDGESC 600000
#define N_GRAPHSC 64
#define D_HIDC   128
#define D_LATC   64
#define D_G      640     // h(128) + mean,mx,mn,std (4*128)
#define D_WROW   1664    // transposed W row length (13*128)

typedef unsigned short u16;
typedef unsigned int   u32;

typedef _Float16 f16x8 __attribute__((ext_vector_type(8)));
typedef float    f32x4 __attribute__((ext_vector_type(4)));

__device__ __forceinline__ u16 f2h(float f) {
    return __builtin_bit_cast(u16, (_Float16)f);
}
__device__ __forceinline__ float h2f(u16 u) {
    return (float)__builtin_bit_cast(_Float16, u);
}

__device__ __forceinline__ void gll16(void* lds, const void* g) {
    // async global->LDS, 16B per lane; HW dest = wave-uniform base + lane*16
    __builtin_amdgcn_global_load_lds(
        (const __attribute__((address_space(1))) void*)g,
        (__attribute__((address_space(3))) void*)lds, 16, 0, 0);
}

// ---------------- setup kernels ----------------

__global__ void k_zero(int* p, int n) {
    int i = blockIdx.x * 256 + threadIdx.x;
    if (i < n) p[i] = 0;
}

__global__ void k_count(const int* __restrict__ dst, int* __restrict__ deg) {
    int e = blockIdx.x * 256 + threadIdx.x;
    if (e < N_EDGESC) atomicAdd(&deg[dst[e]], 1);
}

__global__ void k_scan_part(const int* __restrict__ deg, int* __restrict__ bsum) {
    __shared__ int s[256];
    int idx = blockIdx.x * 256 + threadIdx.x;
    int v = (idx < N_NODESC) ? deg[idx] : 0;
    s[threadIdx.x] = v; __syncthreads();
    for (int o = 128; o > 0; o >>= 1) {
        if (threadIdx.x < o) s[threadIdx.x] += s[threadIdx.x + o];
        __syncthreads();
    }
    if (threadIdx.x == 0) bsum[blockIdx.x] = s[0];
}

__global__ void k_scan_block(int* bsum) {
    __shared__ int s[256];
    int t = threadIdx.x;
    int v = bsum[t];
    s[t] = v; __syncthreads();
    for (int o = 1; o < 256; o <<= 1) {
        int add = (t >= o) ? s[t - o] : 0;
        __syncthreads();
        s[t] += add;
        __syncthreads();
    }
    bsum[t] = s[t] - v;   // exclusive
}

__global__ void k_scan_final(const int* __restrict__ deg, const int* __restrict__ bsum,
                             int* __restrict__ row_off) {
    __shared__ int s[256];
    int t = threadIdx.x;
    int idx = blockIdx.x * 256 + t;
    int v = (idx < N_NODESC) ? deg[idx] : 0;
    s[t] = v; __syncthreads();
    for (int o = 1; o < 256; o <<= 1) {
        int add = (t >= o) ? s[t - o] : 0;
        __syncthreads();
        s[t] += add;
        __syncthreads();
    }
    int excl = s[t] - v + bsum[blockIdx.x];
    if (idx < N_NODESC) row_off[idx] = excl;
    if (idx == 0) row_off[N_NODESC] = N_EDGESC;
}

__global__ void k_logsum(const int* __restrict__ deg, float* dsum) {
    __shared__ float s[256];
    int idx = blockIdx.x * 256 + threadIdx.x;
    float v = (idx < N_NODESC) ? logf((float)deg[idx] + 1.0f) : 0.0f;
    s[threadIdx.x] = v; __syncthreads();
    for (int o = 128; o > 0; o >>= 1) {
        if (threadIdx.x < o) s[threadIdx.x] += s[threadIdx.x + o];
        __syncthreads();
    }
    if (threadIdx.x == 0) atomicAdd(dsum, s[0]);
}

__global__ void k_fill_csr(const int* __restrict__ src, const int* __restrict__ dst,
                           const int* __restrict__ row_off, int* __restrict__ cursor,
                           int* __restrict__ csr_src) {
    int e = blockIdx.x * 256 + threadIdx.x;
    if (e < N_EDGESC) {
        int d = dst[e];
        int pos = row_off[d] + atomicAdd(&cursor[d], 1);
        csr_src[pos] = src[e];
    }
}

__global__ void k_amp_att(const int* __restrict__ deg, const float* __restrict__ dsum,
                          float* __restrict__ amp, float* __restrict__ att) {
    int n = blockIdx.x * 256 + threadIdx.x;
    if (n < N_NODESC) {
        float delta = dsum[0] * (1.0f / (float)N_NODESC);
        float logd = logf((float)deg[n] + 1.0f);
        amp[n] = logd / delta;
        att[n] = delta / fmaxf(logd, 1e-5f);
    }
}

// graph start offsets via binary search over sorted batch
__global__ void k_goff(const int* __restrict__ batch, int* __restrict__ goff) {
    int g = threadIdx.x;
    if (g > N_GRAPHSC) return;
    int lo = 0, hi = N_NODESC;
    while (lo < hi) {
        int mid = (lo + hi) >> 1;
        if (batch[mid] < g) lo = mid + 1; else hi = mid;
    }
    goff[g] = lo;
}

__global__ void k_x2h(const float* __restrict__ x, u16* __restrict__ h) {
    int i = blockIdx.x * 256 + threadIdx.x;
    if (i < N_NODESC * D_HIDC) h[i] = f2h(x[i]);
}

// transpose [1664][128] fp32 -> fp16 [128][1664]
__global__ void k_wconv(const float* __restrict__ W, u16* __restrict__ Wt) {
    int i = blockIdx.x * 256 + threadIdx.x;
    if (i < D_WROW * D_HIDC) {
        int k = i / D_HIDC, j = i % D_HIDC;
        Wt[(size_t)j * D_WROW + k] = f2h(W[i]);
    }
}

// ---------------- per-layer kernels ----------------

// one wave per node; lane owns feature columns 2*lane, 2*lane+1
// writes G[n] = [h(128), mean(128), max(128), min(128), std(128)] fp16
__global__ void __launch_bounds__(256) k_aggregate(
        const u16* __restrict__ h, const int* __restrict__ row_off,
        const int* __restrict__ csr_src, u16* __restrict__ G) {
    int n = blockIdx.x * 4 + (threadIdx.x >> 6);
    if (n >= N_NODESC) return;
    int lane = threadIdx.x & 63;
    int beg = row_off[n], end = row_off[n + 1];
    float s0 = 0.f, s1 = 0.f, q0 = 0.f, q1 = 0.f;
    float mx0 = -3.4e38f, mx1 = -3.4e38f, mn0 = 3.4e38f, mn1 = 3.4e38f;
    int i = beg;
    for (; i + 1 < end; i += 2) {
        int sa = csr_src[i], sb = csr_src[i + 1];
        u32 ua = *(const u32*)(h + (size_t)sa * D_HIDC + 2 * lane);
        u32 ub = *(const u32*)(h + (size_t)sb * D_HIDC + 2 * lane);
        float a0 = h2f((u16)ua), a1 = h2f((u16)(ua >> 16));
        float b0 = h2f((u16)ub), b1 = h2f((u16)(ub >> 16));
        s0 += a0 + b0; s1 += a1 + b1;
        q0 += a0 * a0 + b0 * b0; q1 += a1 * a1 + b1 * b1;
        mx0 = fmaxf(mx0, fmaxf(a0, b0)); mx1 = fmaxf(mx1, fmaxf(a1, b1));
        mn0 = fminf(mn0, fminf(a0, b0)); mn1 = fminf(mn1, fminf(a1, b1));
    }
    if (i < end) {
        int sa = csr_src[i];
        u32 ua = *(const u32*)(h + (size_t)sa * D_HIDC + 2 * lane);
        float a0 = h2f((u16)ua), a1 = h2f((u16)(ua >> 16));
        s0 += a0; s1 += a1;
        q0 += a0 * a0; q1 += a1 * a1;
        mx0 = fmaxf(mx0, a0); mx1 = fmaxf(mx1, a1);
        mn0 = fminf(mn0, a0); mn1 = fminf(mn1, a1);
    }
    int d = end - beg;
    float inv = 1.0f / fmaxf((float)d, 1.0f);
    float mean0 = s0 * inv, mean1 = s1 * inv;
    float std0 = sqrtf(fmaxf(q0 * inv - mean0 * mean0, 0.0f) + 1e-5f);
    float std1 = sqrtf(fmaxf(q1 * inv - mean1 * mean1, 0.0f) + 1e-5f);
    if (d == 0) { mx0 = mx1 = mn0 = mn1 = 0.0f; }
    u16* base = G + (size_t)n * D_G;
    u32 c = 2 * lane;
    *(u32*)(base + c) = *(const u32*)(h + (size_t)n * D_HIDC + c);   // h copy
    #define PACK2(a, b) ((u32)f2h(a) | ((u32)f2h(b) << 16))
    *(u32*)(base + 128 + c) = PACK2(mean0, mean1);
    *(u32*)(base + 256 + c) = PACK2(mx0, mx1);
    *(u32*)(base + 384 + c) = PACK2(mn0, mn1);
    *(u32*)(base + 512 + c) = PACK2(std0, std1);
    #undef PACK2
}

// h_out[n][j] = relu(bias[j] + G[n]*W[0:640][j] + amp[n]*(S*W[640:1152][j])
//                    + att[n]*(S*W[1152:1664][j])),  S = G[n][128:640]
// A-tiles from Wt [j][1664] fp16; B = G rows. 64 nodes / block, grid 782.
__global__ void __launch_bounds__(256) k_gemm(
        const u16* __restrict__ G, const u16* __restrict__ Wt,
        const float* __restrict__ amp, const float* __restrict__ att,
        const float* __restrict__ bias, u16* __restrict__ hout) {
    __shared__ _Float16 A1[128 * 32];   // 8 KB
    __shared__ _Float16 A2[128 * 32];   // 8 KB
    __shared__ _Float16 A3[128 * 32];   // 8 KB
    __shared__ _Float16 Bt[64 * 32];    // 4 KB
    const _Float16* Wf = (const _Float16*)Wt;
    const _Float16* Gf = (const _Float16*)G;
    int n0 = blockIdx.x * 64;
    int t = threadIdx.x;
    int w = t >> 6, lane = t & 63;
    f32x4 c1[2][4], c2[2][4], c3[2][4];
    #pragma unroll
    for (int a = 0; a < 2; a++)
        #pragma unroll
        for (int b = 0; b < 4; b++) {
            c1[a][b] = (f32x4){0.f, 0.f, 0.f, 0.f};
            c2[a][b] = (f32x4){0.f, 0.f, 0.f, 0.f};
            c3[a][b] = (f32x4){0.f, 0.f, 0.f, 0.f};
        }
    int rw4 = lane >> 2;            // 0..15
    int koff = (lane & 3) * 8;      // 0,8,16,24

    for (int ki = 0; ki < D_G / 32; ki++) {
        int k0 = ki * 32;
        __syncthreads();
        #pragma unroll
        for (int r = 0; r < 2; r++) {
            int rr = r * 4 + w;
            int row = rr * 16 + rw4;
            gll16(&A1[rr * 512], Wf + (size_t)row * D_WROW + k0 + koff);
        }
        if (k0 >= 128) {
            int kq = k0 - 128;
            #pragma unroll
            for (int r = 0; r < 2; r++) {
                int rr = r * 4 + w;
                int row = rr * 16 + rw4;
                gll16(&A2[rr * 512], Wf + (size_t)row * D_WROW + 640 + kq + koff);
                gll16(&A3[rr * 512], Wf + (size_t)row * D_WROW + 1152 + kq + koff);
            }
        }
        gll16(&Bt[w * 512], Gf + (size_t)(n0 + w * 16 + rw4) * D_G + k0 + koff);
        __syncthreads();
        int q8 = (lane >> 4) * 8;
        int r16 = lane & 15;
        f16x8 x10 = *(const f16x8*)&A1[(w * 32 + r16) * 32 + q8];
        f16x8 x11 = *(const f16x8*)&A1[(w * 32 + 16 + r16) * 32 + q8];
        if (k0 < 128) {
            #pragma unroll
            for (int nt = 0; nt < 4; nt++) {
                f16x8 b = *(const f16x8*)&Bt[(nt * 16 + r16) * 32 + q8];
                c1[0][nt] = __builtin_amdgcn_mfma_f32_16x16x32_f16(x10, b, c1[0][nt], 0, 0, 0);
                c1[1][nt] = __builtin_amdgcn_mfma_f32_16x16x32_f16(x11, b, c1[1][nt], 0, 0, 0);
            }
        } else {
            f16x8 x20 = *(const f16x8*)&A2[(w * 32 + r16) * 32 + q8];
            f16x8 x21 = *(const f16x8*)&A2[(w * 32 + 16 + r16) * 32 + q8];
            f16x8 x30 = *(const f16x8*)&A3[(w * 32 + r16) * 32 + q8];
            f16x8 x31 = *(const f16x8*)&A3[(w * 32 + 16 + r16) * 32 + q8];
            #pragma unroll
            for (int nt = 0; nt < 4; nt++) {
                f16x8 b = *(const f16x8*)&Bt[(nt * 16 + r16) * 32 + q8];
                c1[0][nt] = __builtin_amdgcn_mfma_f32_16x16x32_f16(x10, b, c1[0][nt], 0, 0, 0);
                c1[1][nt] = __builtin_amdgcn_mfma_f32_16x16x32_f16(x11, b, c1[1][nt], 0, 0, 0);
                c2[0][nt] = __builtin_amdgcn_mfma_f32_16x16x32_f16(x20, b, c2[0][nt], 0, 0, 0);
                c2[1][nt] = __builtin_amdgcn_mfma_f32_16x16x32_f16(x21, b, c2[1][nt], 0, 0, 0);
                c3[0][nt] = __builtin_amdgcn_mfma_f32_16x16x32_f16(x30, b, c3[0][nt], 0, 0, 0);
                c3[1][nt] = __builtin_amdgcn_mfma_f32_16x16x32_f16(x31, b, c3[1][nt], 0, 0, 0);
            }
        }
    }
    // D[row=(lane>>4)*4+reg][col=lane&15]; row -> j, col -> node
    int col = lane & 15;
    int rowq = (lane >> 4) * 4;
    #pragma unroll
    for (int nt = 0; nt < 4; nt++) {
        int node = n0 + nt * 16 + col;
        float am = amp[node], at = att[node];
        #pragma unroll
        for (int mt = 0; mt < 2; mt++) {
            int jb = w * 32 + mt * 16 + rowq;
            f32x4 v1 = c1[mt][nt], v2 = c2[mt][nt], v3 = c3[mt][nt];
            ushort4 o;
            o.x = f2h(fmaxf(v1.x + am * v2.x + at * v3.x + bias[jb], 0.0f));
            o.y = f2h(fmaxf(v1.y + am * v2.y + at * v3.y + bias[jb + 1], 0.0f));
            o.z = f2h(fmaxf(v1.z + am * v2.z + at * v3.z + bias[jb + 2], 0.0f));
            o.w = f2h(fmaxf(v1.w + am * v2.w + at * v3.w + bias[jb + 3], 0.0f));
            *(ushort4*)&hout[(size_t)node * D_HIDC + jb] = o;
        }
    }
}

// ---------------- epilogue kernels ----------------

// 4 segments per graph; 256 blocks x 256 threads; one atomic per (block, j)
__global__ void __launch_bounds__(256) k_pool(
        const u16* __restrict__ h, const int* __restrict__ goff,
        float* __restrict__ pooled) {
    __shared__ float sm[256];
    int g = blockIdx.x >> 2, s = blockIdx.x & 3;
    int gb = goff[g], ge = goff[g + 1];
    int len = ge - gb;
    int q = (len + 3) >> 2;
    int nb = gb + s * q;
    int ne = min(nb + q, ge);
    int t = threadIdx.x;
    int j = t & 127, half = t >> 7;
    float acc = 0.0f;
    for (int n = nb + half; n < ne; n += 2)
        acc += h2f(h[(size_t)n * D_HIDC + j]);
    sm[t] = acc; __syncthreads();
    if (t < 128) {
        float v = sm[t] + sm[t + 128];
        atomicAdd(&pooled[g * D_HIDC + j], v);
    }
}

__global__ void __launch_bounds__(256) k_bn_fc(
        const float* __restrict__ pooled, const float* __restrict__ gamma,
        const float* __restrict__ beta, const float* __restrict__ fcW,
        const float* __restrict__ fcb, float* __restrict__ out) {
    __shared__ float bn[N_GRAPHSC * D_HIDC];   // 32 KB
    int t = threadIdx.x;
    if (t < D_HIDC) {
        float s = 0.f, q = 0.f;
        for (int g = 0; g < N_GRAPHSC; g++) {
            float v = pooled[g * D_HIDC + t];
            s += v; q += v * v;
        }
        float mu = s * (1.0f / N_GRAPHSC);
        float var = q * (1.0f / N_GRAPHSC) - mu * mu;
        float inv = 1.0f / sqrtf(var + 1e-5f);
        float ga = gamma[t], be = beta[t];
        for (int g = 0; g < N_GRAPHSC; g++)
            bn[g * D_HIDC + t] = (pooled[g * D_HIDC + t] - mu) * inv * ga + be;
    }
    __syncthreads();
    for (int o = t; o < N_GRAPHSC * D_LATC; o += 256) {
        int g = o / D_LATC, l = o % D_LATC;
        float accum = fcb[l];
        for (int j = 0; j < D_HIDC; j++) accum += bn[g * D_HIDC + j] * fcW[j * D_LATC + l];
        out[o] = accum;
    }
}

// ---------------- launch ----------------

extern "C" void kernel_launch(void* const* d_in, const int* in_sizes, int n_in,
                              void* d_out, int out_size, void* d_ws, size_t ws_size,
                              hipStream_t stream) {
    const float* x     = (const float*)d_in[0];
    const int*   ei    = (const int*)d_in[1];
    const int*   batch = (const int*)d_in[2];
    const float* W0 = (const float*)d_in[3];
    const float* b0 = (const float*)d_in[4];
    const float* W1 = (const float*)d_in[5];
    const float* b1 = (const float*)d_in[6];
    const float* W2 = (const float*)d_in[7];
    const float* b2 = (const float*)d_in[8];
    const float* gamma = (const float*)d_in[9];
    const float* beta  = (const float*)d_in[10];
    const float* fcW   = (const float*)d_in[11];
    const float* fcb   = (const float*)d_in[12];
    float* out = (float*)d_out;
    const int* srcv = ei;
    const int* dstv = ei + N_EDGESC;

    char* p = (char*)d_ws;
    auto alloc = [&](size_t bytes) -> char* {
        char* r = p;
        p += (bytes + 255) & ~(size_t)255;
        return r;
    };
    int*   deg_cnt = (int*)alloc((size_t)N_NODESC * 4);
    int*   cursor  = (int*)alloc((size_t)N_NODESC * 4);
    int*   bsum    = (int*)alloc(256 * 4);
    float* dsum    = (float*)alloc(4);
    float* pooled  = (float*)alloc((size_t)N_GRAPHSC * D_HIDC * 4);
    char*  zero_end = p;
    int*   row_off = (int*)alloc((size_t)(N_NODESC + 1) * 4);
    int*   goff    = (int*)alloc((size_t)(N_GRAPHSC + 1) * 4);
    int*   csr_src = (int*)alloc((size_t)N_EDGESC * 4);
    float* amp     = (float*)alloc((size_t)N_PAD * 4);
    float* att     = (float*)alloc((size_t)N_PAD * 4);
    u16*   Wt      = (u16*)alloc((size_t)3 * D_WROW * D_HIDC * 2);   // 1.28 MB
    u16*   hA      = (u16*)alloc((size_t)N_PAD * D_HIDC * 2);        // 12.8 MB
    u16*   hB      = (u16*)alloc((size_t)N_PAD * D_HIDC * 2);        // 12.8 MB
    u16*   G       = (u16*)alloc((size_t)N_PAD * D_G * 2);           // 64.1 MB

    int nz = (int)((zero_end - (char*)deg_cnt) / 4);
    k_zero<<<(nz + 255) / 256, 256, 0, stream>>>(deg_cnt, nz);
    k_count<<<(N_EDGESC + 255) / 256, 256, 0, stream>>>(dstv, deg_cnt);
    k_scan_part<<<196, 256, 0, stream>>>(deg_cnt, bsum);
    k_scan_block<<<1, 256, 0, stream>>>(bsum);
    k_scan_final<<<196, 256, 0, stream>>>(deg_cnt, bsum, row_off);
    k_logsum<<<196, 256, 0, stream>>>(deg_cnt, dsum);
    k_fill_csr<<<(N_EDGESC + 255) / 256, 256, 0, stream>>>(srcv, dstv, row_off, cursor, csr_src);
    k_amp_att<<<196, 256, 0, stream>>>(deg_cnt, dsum, amp, att);
    k_goff<<<1, 128, 0, stream>>>(batch, goff);
    k_x2h<<<(N_NODESC * D_HIDC + 255) / 256, 256, 0, stream>>>(x, hB);
    int wgrid = (D_WROW * D_HIDC + 255) / 256;
    size_t wsz = (size_t)D_WROW * D_HIDC;
    k_wconv<<<wgrid, 256, 0, stream>>>(W0, Wt);
    k_wconv<<<wgrid, 256, 0, stream>>>(W1, Wt + wsz);
    k_wconv<<<wgrid, 256, 0, stream>>>(W2, Wt + 2 * wsz);

    const float* bs[3] = {b0, b1, b2};
    const u16* h_in[3]  = {hB, hA, hB};
    u16*       h_out[3] = {hA, hB, hA};
    for (int l = 0; l < 3; l++) {
        k_aggregate<<<(N_NODESC + 3) / 4, 256, 0, stream>>>(
            h_in[l], row_off, csr_src, G);
        k_gemm<<<N_PAD / 64, 256, 0, stream>>>(
            G, Wt + (size_t)l * wsz, amp, att, bs[l], h_out[l]);
    }
    k_pool<<<4 * N_GRAPHSC, 256, 0, stream>>>(h_out[2], goff, pooled);
    k_bn_fc<<<1, 256, 0, stream>>>(pooled, gamma, beta, fcW, fcb, out);
}

// Round 6
// 495.669 us; speedup vs baseline: 2.2345x; 1.1878x over previous
//
#include <hip/hip_runtime.h>
#include <cstdint>
#include <cstddef>

#define N_NODESC 50000
#define N_PAD    50048   // 782 * 64
#define N_EDGESC 600000
#define N_GRAPHSC 64
#define D_HIDC   128
#define D_LATC   64
#define D_G      640     // h(128) + mean,mx,mn,std (4*128)
#define D_WROW   1664    // transposed W row length (13*128)

typedef unsigned short u16;
typedef unsigned int   u32;

typedef _Float16 f16x8 __attribute__((ext_vector_type(8)));
typedef float    f32x4 __attribute__((ext_vector_type(4)));

__device__ __forceinline__ u16 f2h(float f) {
    return __builtin_bit_cast(u16, (_Float16)f);
}
__device__ __forceinline__ float h2f(u16 u) {
    return (float)__builtin_bit_cast(_Float16, u);
}

__device__ __forceinline__ void gll16(void* lds, const void* g) {
    // async global->LDS, 16B per lane; HW dest = wave-uniform base + lane*16
    __builtin_amdgcn_global_load_lds(
        (const __attribute__((address_space(1))) void*)g,
        (__attribute__((address_space(3))) void*)lds, 16, 0, 0);
}

// ---------------- setup kernels ----------------

__global__ void k_zero(int* p, int n) {
    int i = blockIdx.x * 256 + threadIdx.x;
    if (i < n) p[i] = 0;
}

__global__ void k_count(const int* __restrict__ dst, int* __restrict__ deg) {
    int e = blockIdx.x * 256 + threadIdx.x;
    if (e < N_EDGESC) atomicAdd(&deg[dst[e]], 1);
}

__global__ void k_scan_part(const int* __restrict__ deg, int* __restrict__ bsum) {
    __shared__ int s[256];
    int idx = blockIdx.x * 256 + threadIdx.x;
    int v = (idx < N_NODESC) ? deg[idx] : 0;
    s[threadIdx.x] = v; __syncthreads();
    for (int o = 128; o > 0; o >>= 1) {
        if (threadIdx.x < o) s[threadIdx.x] += s[threadIdx.x + o];
        __syncthreads();
    }
    if (threadIdx.x == 0) bsum[blockIdx.x] = s[0];
}

__global__ void k_scan_block(int* bsum) {
    __shared__ int s[256];
    int t = threadIdx.x;
    int v = bsum[t];
    s[t] = v; __syncthreads();
    for (int o = 1; o < 256; o <<= 1) {
        int add = (t >= o) ? s[t - o] : 0;
        __syncthreads();
        s[t] += add;
        __syncthreads();
    }
    bsum[t] = s[t] - v;   // exclusive
}

__global__ void k_scan_final(const int* __restrict__ deg, const int* __restrict__ bsum,
                             int* __restrict__ row_off) {
    __shared__ int s[256];
    int t = threadIdx.x;
    int idx = blockIdx.x * 256 + t;
    int v = (idx < N_NODESC) ? deg[idx] : 0;
    s[t] = v; __syncthreads();
    for (int o = 1; o < 256; o <<= 1) {
        int add = (t >= o) ? s[t - o] : 0;
        __syncthreads();
        s[t] += add;
        __syncthreads();
    }
    int excl = s[t] - v + bsum[blockIdx.x];
    if (idx < N_NODESC) row_off[idx] = excl;
    if (idx == 0) row_off[N_NODESC] = N_EDGESC;
}

__global__ void k_logsum(const int* __restrict__ deg, float* dsum) {
    __shared__ float s[256];
    int idx = blockIdx.x * 256 + threadIdx.x;
    float v = (idx < N_NODESC) ? logf((float)deg[idx] + 1.0f) : 0.0f;
    s[threadIdx.x] = v; __syncthreads();
    for (int o = 128; o > 0; o >>= 1) {
        if (threadIdx.x < o) s[threadIdx.x] += s[threadIdx.x + o];
        __syncthreads();
    }
    if (threadIdx.x == 0) atomicAdd(dsum, s[0]);
}

__global__ void k_fill_csr(const int* __restrict__ src, const int* __restrict__ dst,
                           const int* __restrict__ row_off, int* __restrict__ cursor,
                           int* __restrict__ csr_src) {
    int e = blockIdx.x * 256 + threadIdx.x;
    if (e < N_EDGESC) {
        int d = dst[e];
        int pos = row_off[d] + atomicAdd(&cursor[d], 1);
        csr_src[pos] = src[e];
    }
}

__global__ void k_amp_att(const int* __restrict__ deg, const float* __restrict__ dsum,
                          float* __restrict__ amp, float* __restrict__ att) {
    int n = blockIdx.x * 256 + threadIdx.x;
    if (n < N_PAD) {
        float delta = dsum[0] * (1.0f / (float)N_NODESC);
        float logd = (n < N_NODESC) ? logf((float)deg[n] + 1.0f) : 0.0f;
        amp[n] = logd / delta;
        att[n] = delta / fmaxf(logd, 1e-5f);
    }
}

// graph start offsets via binary search over sorted batch
__global__ void k_goff(const int* __restrict__ batch, int* __restrict__ goff) {
    int g = threadIdx.x;
    if (g > N_GRAPHSC) return;
    int lo = 0, hi = N_NODESC;
    while (lo < hi) {
        int mid = (lo + hi) >> 1;
        if (batch[mid] < g) lo = mid + 1; else hi = mid;
    }
    goff[g] = lo;
}

__global__ void k_x2h(const float* __restrict__ x, u16* __restrict__ h) {
    int i = blockIdx.x * 256 + threadIdx.x;
    if (i < N_NODESC * D_HIDC) h[i] = f2h(x[i]);
}

// transpose [1664][128] fp32 -> fp16 [128][1664]
__global__ void k_wconv(const float* __restrict__ W, u16* __restrict__ Wt) {
    int i = blockIdx.x * 256 + threadIdx.x;
    if (i < D_WROW * D_HIDC) {
        int k = i / D_HIDC, j = i % D_HIDC;
        Wt[(size_t)j * D_WROW + k] = f2h(W[i]);
    }
}

// ---------------- per-layer kernels ----------------

// one wave per node; lane owns feature columns 2*lane, 2*lane+1
// writes G[n] = [h(128), mean(128), max(128), min(128), std(128)] fp16
__global__ void __launch_bounds__(256) k_aggregate(
        const u16* __restrict__ h, const int* __restrict__ row_off,
        const int* __restrict__ csr_src, u16* __restrict__ G) {
    int n = blockIdx.x * 4 + (threadIdx.x >> 6);
    if (n >= N_NODESC) return;
    int lane = threadIdx.x & 63;
    int beg = row_off[n], end = row_off[n + 1];
    float s0 = 0.f, s1 = 0.f, q0 = 0.f, q1 = 0.f;
    float mx0 = -3.4e38f, mx1 = -3.4e38f, mn0 = 3.4e38f, mn1 = 3.4e38f;
    int i = beg;
    for (; i + 1 < end; i += 2) {
        int sa = csr_src[i], sb = csr_src[i + 1];
        u32 ua = *(const u32*)(h + (size_t)sa * D_HIDC + 2 * lane);
        u32 ub = *(const u32*)(h + (size_t)sb * D_HIDC + 2 * lane);
        float a0 = h2f((u16)ua), a1 = h2f((u16)(ua >> 16));
        float b0 = h2f((u16)ub), b1 = h2f((u16)(ub >> 16));
        s0 += a0 + b0; s1 += a1 + b1;
        q0 += a0 * a0 + b0 * b0; q1 += a1 * a1 + b1 * b1;
        mx0 = fmaxf(mx0, fmaxf(a0, b0)); mx1 = fmaxf(mx1, fmaxf(a1, b1));
        mn0 = fminf(mn0, fminf(a0, b0)); mn1 = fminf(mn1, fminf(a1, b1));
    }
    if (i < end) {
        int sa = csr_src[i];
        u32 ua = *(const u32*)(h + (size_t)sa * D_HIDC + 2 * lane);
        float a0 = h2f((u16)ua), a1 = h2f((u16)(ua >> 16));
        s0 += a0; s1 += a1;
        q0 += a0 * a0; q1 += a1 * a1;
        mx0 = fmaxf(mx0, a0); mx1 = fmaxf(mx1, a1);
        mn0 = fminf(mn0, a0); mn1 = fminf(mn1, a1);
    }
    int d = end - beg;
    float inv = 1.0f / fmaxf((float)d, 1.0f);
    float mean0 = s0 * inv, mean1 = s1 * inv;
    float std0 = sqrtf(fmaxf(q0 * inv - mean0 * mean0, 0.0f) + 1e-5f);
    float std1 = sqrtf(fmaxf(q1 * inv - mean1 * mean1, 0.0f) + 1e-5f);
    if (d == 0) { mx0 = mx1 = mn0 = mn1 = 0.0f; }
    u16* base = G + (size_t)n * D_G;
    u32 c = 2 * lane;
    *(u32*)(base + c) = *(const u32*)(h + (size_t)n * D_HIDC + c);   // h copy
    #define PACK2(a, b) ((u32)f2h(a) | ((u32)f2h(b) << 16))
    *(u32*)(base + 128 + c) = PACK2(mean0, mean1);
    *(u32*)(base + 256 + c) = PACK2(mx0, mx1);
    *(u32*)(base + 384 + c) = PACK2(mn0, mn1);
    *(u32*)(base + 512 + c) = PACK2(std0, std1);
    #undef PACK2
}

// h_out[n][j] = relu(bias[j] + G[n]*W1[j] + amp[n]*(S*W2[j]) + att[n]*(S*W3[j]))
// computed with ONE accumulator set via sequential phases and per-lane rescale:
//   ((c2*(am/at) + c3)*at + c1)  ==  c1 + am*c2 + at*c3     (at >= 0.73, never 0)
// BK=64, XOR-swizzled LDS chunks (slot = chunkcol ^ (row&7)) -> conflict-free frags.
__global__ void __launch_bounds__(256) k_gemm(
        const u16* __restrict__ G, const u16* __restrict__ Wt,
        const float* __restrict__ amp, const float* __restrict__ att,
        const float* __restrict__ bias, u16* __restrict__ hout) {
    __shared__ _Float16 At[128 * 64];   // 16 KB
    __shared__ _Float16 Bt[64 * 64];    // 8 KB
    const _Float16* Wf = (const _Float16*)Wt;
    const _Float16* Gf = (const _Float16*)G;
    int n0 = blockIdx.x * 64;
    int t = threadIdx.x;
    int w = t >> 6, lane = t & 63;
    int srow8 = lane >> 3, sslot = lane & 7;
    int stg = (sslot ^ srow8) * 8;        // swizzled source chunk offset (fp16)
    int q4 = lane >> 4, r16 = lane & 15;
    int sx0 = (q4 ^ (lane & 7)) * 8;      // swizzled frag slot, k32=0
    int sx1 = ((q4 + 4) ^ (lane & 7)) * 8;// swizzled frag slot, k32=32
    int col = lane & 15;

    float s1v[4], s2v[4];
    #pragma unroll
    for (int nt = 0; nt < 4; nt++) {
        int node = n0 + nt * 16 + col;
        float am = amp[node], at = att[node];
        s2v[nt] = at;
        s1v[nt] = am / at;
    }

    f32x4 acc[2][4];
    #pragma unroll
    for (int a = 0; a < 2; a++)
        #pragma unroll
        for (int b = 0; b < 4; b++) acc[a][b] = (f32x4){0.f, 0.f, 0.f, 0.f};

    #pragma unroll
    for (int ph = 0; ph < 3; ph++) {
        const int wbase = (ph == 0) ? 640 : (ph == 1) ? 1152 : 0;
        const int gbase = (ph == 2) ? 0 : 128;
        const int iters = (ph == 2) ? 10 : 8;
        for (int ki = 0; ki < iters; ki++) {
            int k0 = ki * 64;
            __syncthreads();
            #pragma unroll
            for (int r = 0; r < 4; r++) {
                int arow = (r * 4 + w) * 8 + srow8;
                gll16(&At[(r * 4 + w) * 512],
                      Wf + (size_t)arow * D_WROW + wbase + k0 + stg);
            }
            #pragma unroll
            for (int q = 0; q < 2; q++) {
                int brow = (q * 4 + w) * 8 + srow8;
                gll16(&Bt[(q * 4 + w) * 512],
                      Gf + (size_t)(n0 + brow) * D_G + gbase + k0 + stg);
            }
            __syncthreads();
            f16x8 a00 = *(const f16x8*)&At[(w * 32 + r16) * 64 + sx0];
            f16x8 a01 = *(const f16x8*)&At[(w * 32 + r16) * 64 + sx1];
            f16x8 a10 = *(const f16x8*)&At[(w * 32 + 16 + r16) * 64 + sx0];
            f16x8 a11 = *(const f16x8*)&At[(w * 32 + 16 + r16) * 64 + sx1];
            #pragma unroll
            for (int nt = 0; nt < 4; nt++) {
                f16x8 b0 = *(const f16x8*)&Bt[(nt * 16 + r16) * 64 + sx0];
                f16x8 b1 = *(const f16x8*)&Bt[(nt * 16 + r16) * 64 + sx1];
                acc[0][nt] = __builtin_amdgcn_mfma_f32_16x16x32_f16(a00, b0, acc[0][nt], 0, 0, 0);
                acc[1][nt] = __builtin_amdgcn_mfma_f32_16x16x32_f16(a10, b0, acc[1][nt], 0, 0, 0);
                acc[0][nt] = __builtin_amdgcn_mfma_f32_16x16x32_f16(a01, b1, acc[0][nt], 0, 0, 0);
                acc[1][nt] = __builtin_amdgcn_mfma_f32_16x16x32_f16(a11, b1, acc[1][nt], 0, 0, 0);
            }
        }
        if (ph < 2) {
            #pragma unroll
            for (int nt = 0; nt < 4; nt++) {
                float s = (ph == 0) ? s1v[nt] : s2v[nt];
                #pragma unroll
                for (int mt = 0; mt < 2; mt++) {
                    acc[mt][nt].x *= s; acc[mt][nt].y *= s;
                    acc[mt][nt].z *= s; acc[mt][nt].w *= s;
                }
            }
        }
    }
    // D[row=(lane>>4)*4+reg][col=lane&15]; row -> j, col -> node
    int rowq = q4 * 4;
    #pragma unroll
    for (int nt = 0; nt < 4; nt++) {
        int node = n0 + nt * 16 + col;
        #pragma unroll
        for (int mt = 0; mt < 2; mt++) {
            int jb = w * 32 + mt * 16 + rowq;
            f32x4 v = acc[mt][nt];
            ushort4 o;
            o.x = f2h(fmaxf(v.x + bias[jb], 0.0f));
            o.y = f2h(fmaxf(v.y + bias[jb + 1], 0.0f));
            o.z = f2h(fmaxf(v.z + bias[jb + 2], 0.0f));
            o.w = f2h(fmaxf(v.w + bias[jb + 3], 0.0f));
            *(ushort4*)&hout[(size_t)node * D_HIDC + jb] = o;
        }
    }
}

// ---------------- epilogue kernels ----------------

// 4 segments per graph; 256 blocks x 256 threads; one atomic per (block, j)
__global__ void __launch_bounds__(256) k_pool(
        const u16* __restrict__ h, const int* __restrict__ goff,
        float* __restrict__ pooled) {
    __shared__ float sm[256];
    int g = blockIdx.x >> 2, s = blockIdx.x & 3;
    int gb = goff[g], ge = goff[g + 1];
    int len = ge - gb;
    int q = (len + 3) >> 2;
    int nb = gb + s * q;
    int ne = min(nb + q, ge);
    int t = threadIdx.x;
    int j = t & 127, half = t >> 7;
    float acc = 0.0f;
    for (int n = nb + half; n < ne; n += 2)
        acc += h2f(h[(size_t)n * D_HIDC + j]);
    sm[t] = acc; __syncthreads();
    if (t < 128) {
        float v = sm[t] + sm[t + 128];
        atomicAdd(&pooled[g * D_HIDC + j], v);
    }
}

__global__ void __launch_bounds__(256) k_bn_fc(
        const float* __restrict__ pooled, const float* __restrict__ gamma,
        const float* __restrict__ beta, const float* __restrict__ fcW,
        const float* __restrict__ fcb, float* __restrict__ out) {
    __shared__ float bn[N_GRAPHSC * D_HIDC];   // 32 KB
    int t = threadIdx.x;
    if (t < D_HIDC) {
        float s = 0.f, q = 0.f;
        for (int g = 0; g < N_GRAPHSC; g++) {
            float v = pooled[g * D_HIDC + t];
            s += v; q += v * v;
        }
        float mu = s * (1.0f / N_GRAPHSC);
        float var = q * (1.0f / N_GRAPHSC) - mu * mu;
        float inv = 1.0f / sqrtf(var + 1e-5f);
        float ga = gamma[t], be = beta[t];
        for (int g = 0; g < N_GRAPHSC; g++)
            bn[g * D_HIDC + t] = (pooled[g * D_HIDC + t] - mu) * inv * ga + be;
    }
    __syncthreads();
    for (int o = t; o < N_GRAPHSC * D_LATC; o += 256) {
        int g = o / D_LATC, l = o % D_LATC;
        float accum = fcb[l];
        for (int j = 0; j < D_HIDC; j++) accum += bn[g * D_HIDC + j] * fcW[j * D_LATC + l];
        out[o] = accum;
    }
}

// ---------------- launch ----------------

extern "C" void kernel_launch(void* const* d_in, const int* in_sizes, int n_in,
                              void* d_out, int out_size, void* d_ws, size_t ws_size,
                              hipStream_t stream) {
    const float* x     = (const float*)d_in[0];
    const int*   ei    = (const int*)d_in[1];
    const int*   batch = (const int*)d_in[2];
    const float* W0 = (const float*)d_in[3];
    const float* b0 = (const float*)d_in[4];
    const float* W1 = (const float*)d_in[5];
    const float* b1 = (const float*)d_in[6];
    const float* W2 = (const float*)d_in[7];
    const float* b2 = (const float*)d_in[8];
    const float* gamma = (const float*)d_in[9];
    const float* beta  = (const float*)d_in[10];
    const float* fcW   = (const float*)d_in[11];
    const float* fcb   = (const float*)d_in[12];
    float* out = (float*)d_out;
    const int* srcv = ei;
    const int* dstv = ei + N_EDGESC;

    char* p = (char*)d_ws;
    auto alloc = [&](size_t bytes) -> char* {
        char* r = p;
        p += (bytes + 255) & ~(size_t)255;
        return r;
    };
    int*   deg_cnt = (int*)alloc((size_t)N_NODESC * 4);
    int*   cursor  = (int*)alloc((size_t)N_NODESC * 4);
    int*   bsum    = (int*)alloc(256 * 4);
    float* dsum    = (float*)alloc(4);
    float* pooled  = (float*)alloc((size_t)N_GRAPHSC * D_HIDC * 4);
    char*  zero_end = p;
    int*   row_off = (int*)alloc((size_t)(N_NODESC + 1) * 4);
    int*   goff    = (int*)alloc((size_t)(N_GRAPHSC + 1) * 4);
    int*   csr_src = (int*)alloc((size_t)N_EDGESC * 4);
    float* amp     = (float*)alloc((size_t)N_PAD * 4);
    float* att     = (float*)alloc((size_t)N_PAD * 4);
    u16*   Wt      = (u16*)alloc((size_t)3 * D_WROW * D_HIDC * 2);   // 1.28 MB
    u16*   hA      = (u16*)alloc((size_t)N_PAD * D_HIDC * 2);        // 12.8 MB
    u16*   hB      = (u16*)alloc((size_t)N_PAD * D_HIDC * 2);        // 12.8 MB
    u16*   G       = (u16*)alloc((size_t)N_PAD * D_G * 2);           // 64.1 MB

    int nz = (int)((zero_end - (char*)deg_cnt) / 4);
    k_zero<<<(nz + 255) / 256, 256, 0, stream>>>(deg_cnt, nz);
    k_count<<<(N_EDGESC + 255) / 256, 256, 0, stream>>>(dstv, deg_cnt);
    k_scan_part<<<196, 256, 0, stream>>>(deg_cnt, bsum);
    k_scan_block<<<1, 256, 0, stream>>>(bsum);
    k_scan_final<<<196, 256, 0, stream>>>(deg_cnt, bsum, row_off);
    k_logsum<<<196, 256, 0, stream>>>(deg_cnt, dsum);
    k_fill_csr<<<(N_EDGESC + 255) / 256, 256, 0, stream>>>(srcv, dstv, row_off, cursor, csr_src);
    k_amp_att<<<(N_PAD + 255) / 256, 256, 0, stream>>>(deg_cnt, dsum, amp, att);
    k_goff<<<1, 128, 0, stream>>>(batch, goff);
    k_x2h<<<(N_NODESC * D_HIDC + 255) / 256, 256, 0, stream>>>(x, hB);
    int wgrid = (D_WROW * D_HIDC + 255) / 256;
    size_t wsz = (size_t)D_WROW * D_HIDC;
    k_wconv<<<wgrid, 256, 0, stream>>>(W0, Wt);
    k_wconv<<<wgrid, 256, 0, stream>>>(W1, Wt + wsz);
    k_wconv<<<wgrid, 256, 0, stream>>>(W2, Wt + 2 * wsz);

    const float* bs[3] = {b0, b1, b2};
    const u16* h_in[3]  = {hB, hA, hB};
    u16*       h_out[3] = {hA, hB, hA};
    for (int l = 0; l < 3; l++) {
        k_aggregate<<<(N_NODESC + 3) / 4, 256, 0, stream>>>(
            h_in[l], row_off, csr_src, G);
        k_gemm<<<N_PAD / 64, 256, 0, stream>>>(
            G, Wt + (size_t)l * wsz, amp, att, bs[l], h_out[l]);
    }
    k_pool<<<4 * N_GRAPHSC, 256, 0, stream>>>(h_out[2], goff, pooled);
    k_bn_fc<<<1, 256, 0, stream>>>(pooled, gamma, beta, fcW, fcb, out);
}

// Round 7
// 484.423 us; speedup vs baseline: 2.2863x; 1.0232x over previous
//
#include <hip/hip_runtime.h>
#include <cstdint>
#include <cstddef>

#define N_NODESC 50000
#define N_PAD    50048   // 782 * 64
#define N_EDGESC 600000
#define N_GRAPHSC 64
#define D_HIDC   128
#define D_LATC   64
#define D_G      640     // h(128) + mean,mx,mn,std (4*128)
#define D_WROW   1664    // transposed W row length (13*128)

typedef unsigned short u16;
typedef unsigned int   u32;

typedef _Float16 f16x8 __attribute__((ext_vector_type(8)));
typedef float    f32x4 __attribute__((ext_vector_type(4)));

__device__ __forceinline__ u16 f2h(float f) {
    return __builtin_bit_cast(u16, (_Float16)f);
}
__device__ __forceinline__ float h2f(u16 u) {
    return (float)__builtin_bit_cast(_Float16, u);
}

__device__ __forceinline__ void gll16(void* lds, const void* g) {
    // async global->LDS, 16B per lane; HW dest = wave-uniform base + lane*16
    __builtin_amdgcn_global_load_lds(
        (const __attribute__((address_space(1))) void*)g,
        (__attribute__((address_space(3))) void*)lds, 16, 0, 0);
}

// ---------------- setup kernels ----------------

__global__ void k_zero(int* p, int n) {
    int i = blockIdx.x * 256 + threadIdx.x;
    if (i < n) p[i] = 0;
}

__global__ void k_count(const int* __restrict__ dst, int* __restrict__ deg) {
    int e = blockIdx.x * 256 + threadIdx.x;
    if (e < N_EDGESC) atomicAdd(&deg[dst[e]], 1);
}

__global__ void k_scan_part(const int* __restrict__ deg, int* __restrict__ bsum) {
    __shared__ int s[256];
    int idx = blockIdx.x * 256 + threadIdx.x;
    int v = (idx < N_NODESC) ? deg[idx] : 0;
    s[threadIdx.x] = v; __syncthreads();
    for (int o = 128; o > 0; o >>= 1) {
        if (threadIdx.x < o) s[threadIdx.x] += s[threadIdx.x + o];
        __syncthreads();
    }
    if (threadIdx.x == 0) bsum[blockIdx.x] = s[0];
}

__global__ void k_scan_block(int* bsum) {
    __shared__ int s[256];
    int t = threadIdx.x;
    int v = bsum[t];
    s[t] = v; __syncthreads();
    for (int o = 1; o < 256; o <<= 1) {
        int add = (t >= o) ? s[t - o] : 0;
        __syncthreads();
        s[t] += add;
        __syncthreads();
    }
    bsum[t] = s[t] - v;   // exclusive
}

__global__ void k_scan_final(const int* __restrict__ deg, const int* __restrict__ bsum,
                             int* __restrict__ row_off) {
    __shared__ int s[256];
    int t = threadIdx.x;
    int idx = blockIdx.x * 256 + t;
    int v = (idx < N_NODESC) ? deg[idx] : 0;
    s[t] = v; __syncthreads();
    for (int o = 1; o < 256; o <<= 1) {
        int add = (t >= o) ? s[t - o] : 0;
        __syncthreads();
        s[t] += add;
        __syncthreads();
    }
    int excl = s[t] - v + bsum[blockIdx.x];
    if (idx < N_NODESC) row_off[idx] = excl;
    if (idx == 0) row_off[N_NODESC] = N_EDGESC;
}

__global__ void k_logsum(const int* __restrict__ deg, float* dsum) {
    __shared__ float s[256];
    int idx = blockIdx.x * 256 + threadIdx.x;
    float v = (idx < N_NODESC) ? logf((float)deg[idx] + 1.0f) : 0.0f;
    s[threadIdx.x] = v; __syncthreads();
    for (int o = 128; o > 0; o >>= 1) {
        if (threadIdx.x < o) s[threadIdx.x] += s[threadIdx.x + o];
        __syncthreads();
    }
    if (threadIdx.x == 0) atomicAdd(dsum, s[0]);
}

__global__ void k_fill_csr(const int* __restrict__ src, const int* __restrict__ dst,
                           const int* __restrict__ row_off, int* __restrict__ cursor,
                           int* __restrict__ csr_src) {
    int e = blockIdx.x * 256 + threadIdx.x;
    if (e < N_EDGESC) {
        int d = dst[e];
        int pos = row_off[d] + atomicAdd(&cursor[d], 1);
        csr_src[pos] = src[e];
    }
}

__global__ void k_amp_att(const int* __restrict__ deg, const float* __restrict__ dsum,
                          float* __restrict__ amp, float* __restrict__ att) {
    int n = blockIdx.x * 256 + threadIdx.x;
    if (n < N_PAD) {
        float delta = dsum[0] * (1.0f / (float)N_NODESC);
        float logd = (n < N_NODESC) ? logf((float)deg[n] + 1.0f) : 0.0f;
        amp[n] = logd / delta;
        att[n] = delta / fmaxf(logd, 1e-5f);
    }
}

// graph start offsets via binary search over sorted batch
__global__ void k_goff(const int* __restrict__ batch, int* __restrict__ goff) {
    int g = threadIdx.x;
    if (g > N_GRAPHSC) return;
    int lo = 0, hi = N_NODESC;
    while (lo < hi) {
        int mid = (lo + hi) >> 1;
        if (batch[mid] < g) lo = mid + 1; else hi = mid;
    }
    goff[g] = lo;
}

__global__ void k_x2h(const float* __restrict__ x, u16* __restrict__ h) {
    int i = blockIdx.x * 256 + threadIdx.x;
    if (i < N_NODESC * D_HIDC) h[i] = f2h(x[i]);
}

// transpose [1664][128] fp32 -> fp16 [128][1664]
__global__ void k_wconv(const float* __restrict__ W, u16* __restrict__ Wt) {
    int i = blockIdx.x * 256 + threadIdx.x;
    if (i < D_WROW * D_HIDC) {
        int k = i / D_HIDC, j = i % D_HIDC;
        Wt[(size_t)j * D_WROW + k] = f2h(W[i]);
    }
}

// ---------------- per-layer kernels ----------------

// one wave per node; two half-waves process alternate edges of the node.
// lane owns 4 feature columns (8B load per lane); cross-half merge via shfl_xor.
// writes G[n] = [h(128), mean(128), max(128), min(128), std(128)] fp16
__global__ void __launch_bounds__(256) k_aggregate(
        const u16* __restrict__ h, const int* __restrict__ row_off,
        const int* __restrict__ csr_src, u16* __restrict__ G) {
    int n = blockIdx.x * 4 + (threadIdx.x >> 6);
    if (n >= N_NODESC) return;
    int lane = threadIdx.x & 63;
    int half = lane >> 5, l32 = lane & 31;
    int c4 = 4 * l32;                       // first of 4 owned fp16 columns
    int beg = row_off[n], end = row_off[n + 1];
    float s0 = 0.f, s1 = 0.f, s2 = 0.f, s3 = 0.f;
    float q0 = 0.f, q1 = 0.f, q2 = 0.f, q3 = 0.f;
    float mx0 = -3.4e38f, mx1 = -3.4e38f, mx2 = -3.4e38f, mx3 = -3.4e38f;
    float mn0 = 3.4e38f, mn1 = 3.4e38f, mn2 = 3.4e38f, mn3 = 3.4e38f;

    #define PROC(u) { \
        float a0 = h2f((u16)(u).x), a1 = h2f((u16)((u).x >> 16)); \
        float a2 = h2f((u16)(u).y), a3 = h2f((u16)((u).y >> 16)); \
        s0 += a0; s1 += a1; s2 += a2; s3 += a3; \
        q0 += a0 * a0; q1 += a1 * a1; q2 += a2 * a2; q3 += a3 * a3; \
        mx0 = fmaxf(mx0, a0); mx1 = fmaxf(mx1, a1); \
        mx2 = fmaxf(mx2, a2); mx3 = fmaxf(mx3, a3); \
        mn0 = fminf(mn0, a0); mn1 = fminf(mn1, a1); \
        mn2 = fminf(mn2, a2); mn3 = fminf(mn3, a3); }

    int i = beg + half;
    for (; i + 2 < end; i += 4) {
        int ea = csr_src[i], eb = csr_src[i + 2];
        uint2 ua = *(const uint2*)(h + (size_t)ea * D_HIDC + c4);
        uint2 ub = *(const uint2*)(h + (size_t)eb * D_HIDC + c4);
        PROC(ua);
        PROC(ub);
    }
    if (i < end) {
        int ea = csr_src[i];
        uint2 ua = *(const uint2*)(h + (size_t)ea * D_HIDC + c4);
        PROC(ua);
    }
    #undef PROC

    // merge the two half-waves (lane ^ 32 holds same columns, other edges)
    s0 += __shfl_xor(s0, 32); s1 += __shfl_xor(s1, 32);
    s2 += __shfl_xor(s2, 32); s3 += __shfl_xor(s3, 32);
    q0 += __shfl_xor(q0, 32); q1 += __shfl_xor(q1, 32);
    q2 += __shfl_xor(q2, 32); q3 += __shfl_xor(q3, 32);
    mx0 = fmaxf(mx0, __shfl_xor(mx0, 32)); mx1 = fmaxf(mx1, __shfl_xor(mx1, 32));
    mx2 = fmaxf(mx2, __shfl_xor(mx2, 32)); mx3 = fmaxf(mx3, __shfl_xor(mx3, 32));
    mn0 = fminf(mn0, __shfl_xor(mn0, 32)); mn1 = fminf(mn1, __shfl_xor(mn1, 32));
    mn2 = fminf(mn2, __shfl_xor(mn2, 32)); mn3 = fminf(mn3, __shfl_xor(mn3, 32));

    int d = end - beg;
    float inv = 1.0f / fmaxf((float)d, 1.0f);
    float me0 = s0 * inv, me1 = s1 * inv, me2 = s2 * inv, me3 = s3 * inv;
    float sd0 = sqrtf(fmaxf(q0 * inv - me0 * me0, 0.0f) + 1e-5f);
    float sd1 = sqrtf(fmaxf(q1 * inv - me1 * me1, 0.0f) + 1e-5f);
    float sd2 = sqrtf(fmaxf(q2 * inv - me2 * me2, 0.0f) + 1e-5f);
    float sd3 = sqrtf(fmaxf(q3 * inv - me3 * me3, 0.0f) + 1e-5f);
    if (d == 0) {
        mx0 = mx1 = mx2 = mx3 = 0.0f;
        mn0 = mn1 = mn2 = mn3 = 0.0f;
    }
    u16* base = G + (size_t)n * D_G;
    #define PK2(a, b) ((u32)f2h(a) | ((u32)f2h(b) << 16))
    if (half == 0) {
        *(uint2*)(base + c4) = *(const uint2*)(h + (size_t)n * D_HIDC + c4);
        uint2 m; m.x = PK2(me0, me1); m.y = PK2(me2, me3);
        *(uint2*)(base + 128 + c4) = m;
        uint2 X; X.x = PK2(mx0, mx1); X.y = PK2(mx2, mx3);
        *(uint2*)(base + 256 + c4) = X;
    } else {
        uint2 N_; N_.x = PK2(mn0, mn1); N_.y = PK2(mn2, mn3);
        *(uint2*)(base + 384 + c4) = N_;
        uint2 S; S.x = PK2(sd0, sd1); S.y = PK2(sd2, sd3);
        *(uint2*)(base + 512 + c4) = S;
    }
    #undef PK2
}

// h_out[n][j] = relu(bias[j] + G[n]*W1[j] + amp[n]*(S*W2[j]) + att[n]*(S*W3[j]))
// computed with ONE accumulator set via sequential phases and per-lane rescale:
//   ((c2*(am/at) + c3)*at + c1)  ==  c1 + am*c2 + at*c3     (at >= 0.73, never 0)
// BK=64, XOR-swizzled LDS chunks (slot = chunkcol ^ (row&7)) -> conflict-free frags.
__global__ void __launch_bounds__(256) k_gemm(
        const u16* __restrict__ G, const u16* __restrict__ Wt,
        const float* __restrict__ amp, const float* __restrict__ att,
        const float* __restrict__ bias, u16* __restrict__ hout) {
    __shared__ _Float16 At[128 * 64];   // 16 KB
    __shared__ _Float16 Bt[64 * 64];    // 8 KB
    const _Float16* Wf = (const _Float16*)Wt;
    const _Float16* Gf = (const _Float16*)G;
    int n0 = blockIdx.x * 64;
    int t = threadIdx.x;
    int w = t >> 6, lane = t & 63;
    int srow8 = lane >> 3, sslot = lane & 7;
    int stg = (sslot ^ srow8) * 8;        // swizzled source chunk offset (fp16)
    int q4 = lane >> 4, r16 = lane & 15;
    int sx0 = (q4 ^ (lane & 7)) * 8;      // swizzled frag slot, k32=0
    int sx1 = ((q4 + 4) ^ (lane & 7)) * 8;// swizzled frag slot, k32=32
    int col = lane & 15;

    float s1v[4], s2v[4];
    #pragma unroll
    for (int nt = 0; nt < 4; nt++) {
        int node = n0 + nt * 16 + col;
        float am = amp[node], at = att[node];
        s2v[nt] = at;
        s1v[nt] = am / at;
    }

    f32x4 acc[2][4];
    #pragma unroll
    for (int a = 0; a < 2; a++)
        #pragma unroll
        for (int b = 0; b < 4; b++) acc[a][b] = (f32x4){0.f, 0.f, 0.f, 0.f};

    #pragma unroll
    for (int ph = 0; ph < 3; ph++) {
        const int wbase = (ph == 0) ? 640 : (ph == 1) ? 1152 : 0;
        const int gbase = (ph == 2) ? 0 : 128;
        const int iters = (ph == 2) ? 10 : 8;
        for (int ki = 0; ki < iters; ki++) {
            int k0 = ki * 64;
            __syncthreads();
            #pragma unroll
            for (int r = 0; r < 4; r++) {
                int arow = (r * 4 + w) * 8 + srow8;
                gll16(&At[(r * 4 + w) * 512],
                      Wf + (size_t)arow * D_WROW + wbase + k0 + stg);
            }
            #pragma unroll
            for (int q = 0; q < 2; q++) {
                int brow = (q * 4 + w) * 8 + srow8;
                gll16(&Bt[(q * 4 + w) * 512],
                      Gf + (size_t)(n0 + brow) * D_G + gbase + k0 + stg);
            }
            __syncthreads();
            f16x8 a00 = *(const f16x8*)&At[(w * 32 + r16) * 64 + sx0];
            f16x8 a01 = *(const f16x8*)&At[(w * 32 + r16) * 64 + sx1];
            f16x8 a10 = *(const f16x8*)&At[(w * 32 + 16 + r16) * 64 + sx0];
            f16x8 a11 = *(const f16x8*)&At[(w * 32 + 16 + r16) * 64 + sx1];
            #pragma unroll
            for (int nt = 0; nt < 4; nt++) {
                f16x8 b0 = *(const f16x8*)&Bt[(nt * 16 + r16) * 64 + sx0];
                f16x8 b1 = *(const f16x8*)&Bt[(nt * 16 + r16) * 64 + sx1];
                acc[0][nt] = __builtin_amdgcn_mfma_f32_16x16x32_f16(a00, b0, acc[0][nt], 0, 0, 0);
                acc[1][nt] = __builtin_amdgcn_mfma_f32_16x16x32_f16(a10, b0, acc[1][nt], 0, 0, 0);
                acc[0][nt] = __builtin_amdgcn_mfma_f32_16x16x32_f16(a01, b1, acc[0][nt], 0, 0, 0);
                acc[1][nt] = __builtin_amdgcn_mfma_f32_16x16x32_f16(a11, b1, acc[1][nt], 0, 0, 0);
            }
        }
        if (ph < 2) {
            #pragma unroll
            for (int nt = 0; nt < 4; nt++) {
                float s = (ph == 0) ? s1v[nt] : s2v[nt];
                #pragma unroll
                for (int mt = 0; mt < 2; mt++) {
                    acc[mt][nt].x *= s; acc[mt][nt].y *= s;
                    acc[mt][nt].z *= s; acc[mt][nt].w *= s;
                }
            }
        }
    }
    // D[row=(lane>>4)*4+reg][col=lane&15]; row -> j, col -> node
    int rowq = q4 * 4;
    #pragma unroll
    for (int nt = 0; nt < 4; nt++) {
        int node = n0 + nt * 16 + col;
        #pragma unroll
        for (int mt = 0; mt < 2; mt++) {
            int jb = w * 32 + mt * 16 + rowq;
            f32x4 v = acc[mt][nt];
            ushort4 o;
            o.x = f2h(fmaxf(v.x + bias[jb], 0.0f));
            o.y = f2h(fmaxf(v.y + bias[jb + 1], 0.0f));
            o.z = f2h(fmaxf(v.z + bias[jb + 2], 0.0f));
            o.w = f2h(fmaxf(v.w + bias[jb + 3], 0.0f));
            *(ushort4*)&hout[(size_t)node * D_HIDC + jb] = o;
        }
    }
}

// ---------------- epilogue kernels ----------------

// 4 segments per graph; 256 blocks x 256 threads; one atomic per (block, j)
__global__ void __launch_bounds__(256) k_pool(
        const u16* __restrict__ h, const int* __restrict__ goff,
        float* __restrict__ pooled) {
    __shared__ float sm[256];
    int g = blockIdx.x >> 2, s = blockIdx.x & 3;
    int gb = goff[g], ge = goff[g + 1];
    int len = ge - gb;
    int q = (len + 3) >> 2;
    int nb = gb + s * q;
    int ne = min(nb + q, ge);
    int t = threadIdx.x;
    int j = t & 127, half = t >> 7;
    float acc = 0.0f;
    for (int n = nb + half; n < ne; n += 2)
        acc += h2f(h[(size_t)n * D_HIDC + j]);
    sm[t] = acc; __syncthreads();
    if (t < 128) {
        float v = sm[t] + sm[t + 128];
        atomicAdd(&pooled[g * D_HIDC + j], v);
    }
}

__global__ void __launch_bounds__(256) k_bn_fc(
        const float* __restrict__ pooled, const float* __restrict__ gamma,
        const float* __restrict__ beta, const float* __restrict__ fcW,
        const float* __restrict__ fcb, float* __restrict__ out) {
    __shared__ float bn[N_GRAPHSC * D_HIDC];   // 32 KB
    int t = threadIdx.x;
    if (t < D_HIDC) {
        float s = 0.f, q = 0.f;
        for (int g = 0; g < N_GRAPHSC; g++) {
            float v = pooled[g * D_HIDC + t];
            s += v; q += v * v;
        }
        float mu = s * (1.0f / N_GRAPHSC);
        float var = q * (1.0f / N_GRAPHSC) - mu * mu;
        float inv = 1.0f / sqrtf(var + 1e-5f);
        float ga = gamma[t], be = beta[t];
        for (int g = 0; g < N_GRAPHSC; g++)
            bn[g * D_HIDC + t] = (pooled[g * D_HIDC + t] - mu) * inv * ga + be;
    }
    __syncthreads();
    for (int o = t; o < N_GRAPHSC * D_LATC; o += 256) {
        int g = o / D_LATC, l = o % D_LATC;
        float accum = fcb[l];
        for (int j = 0; j < D_HIDC; j++) accum += bn[g * D_HIDC + j] * fcW[j * D_LATC + l];
        out[o] = accum;
    }
}

// ---------------- launch ----------------

extern "C" void kernel_launch(void* const* d_in, const int* in_sizes, int n_in,
                              void* d_out, int out_size, void* d_ws, size_t ws_size,
                              hipStream_t stream) {
    const float* x     = (const float*)d_in[0];
    const int*   ei    = (const int*)d_in[1];
    const int*   batch = (const int*)d_in[2];
    const float* W0 = (const float*)d_in[3];
    const float* b0 = (const float*)d_in[4];
    const float* W1 = (const float*)d_in[5];
    const float* b1 = (const float*)d_in[6];
    const float* W2 = (const float*)d_in[7];
    const float* b2 = (const float*)d_in[8];
    const float* gamma = (const float*)d_in[9];
    const float* beta  = (const float*)d_in[10];
    const float* fcW   = (const float*)d_in[11];
    const float* fcb   = (const float*)d_in[12];
    float* out = (float*)d_out;
    const int* srcv = ei;
    const int* dstv = ei + N_EDGESC;

    char* p = (char*)d_ws;
    auto alloc = [&](size_t bytes) -> char* {
        char* r = p;
        p += (bytes + 255) & ~(size_t)255;
        return r;
    };
    int*   deg_cnt = (int*)alloc((size_t)N_NODESC * 4);
    int*   cursor  = (int*)alloc((size_t)N_NODESC * 4);
    int*   bsum    = (int*)alloc(256 * 4);
    float* dsum    = (float*)alloc(4);
    float* pooled  = (float*)alloc((size_t)N_GRAPHSC * D_HIDC * 4);
    char*  zero_end = p;
    int*   row_off = (int*)alloc((size_t)(N_NODESC + 1) * 4);
    int*   goff    = (int*)alloc((size_t)(N_GRAPHSC + 1) * 4);
    int*   csr_src = (int*)alloc((size_t)N_EDGESC * 4);
    float* amp     = (float*)alloc((size_t)N_PAD * 4);
    float* att     = (float*)alloc((size_t)N_PAD * 4);
    u16*   Wt      = (u16*)alloc((size_t)3 * D_WROW * D_HIDC * 2);   // 1.28 MB
    u16*   hA      = (u16*)alloc((size_t)N_PAD * D_HIDC * 2);        // 12.8 MB
    u16*   hB      = (u16*)alloc((size_t)N_PAD * D_HIDC * 2);        // 12.8 MB
    u16*   G       = (u16*)alloc((size_t)N_PAD * D_G * 2);           // 64.1 MB

    int nz = (int)((zero_end - (char*)deg_cnt) / 4);
    k_zero<<<(nz + 255) / 256, 256, 0, stream>>>(deg_cnt, nz);
    k_count<<<(N_EDGESC + 255) / 256, 256, 0, stream>>>(dstv, deg_cnt);
    k_scan_part<<<196, 256, 0, stream>>>(deg_cnt, bsum);
    k_scan_block<<<1, 256, 0, stream>>>(bsum);
    k_scan_final<<<196, 256, 0, stream>>>(deg_cnt, bsum, row_off);
    k_logsum<<<196, 256, 0, stream>>>(deg_cnt, dsum);
    k_fill_csr<<<(N_EDGESC + 255) / 256, 256, 0, stream>>>(srcv, dstv, row_off, cursor, csr_src);
    k_amp_att<<<(N_PAD + 255) / 256, 256, 0, stream>>>(deg_cnt, dsum, amp, att);
    k_goff<<<1, 128, 0, stream>>>(batch, goff);
    k_x2h<<<(N_NODESC * D_HIDC + 255) / 256, 256, 0, stream>>>(x, hB);
    int wgrid = (D_WROW * D_HIDC + 255) / 256;
    size_t wsz = (size_t)D_WROW * D_HIDC;
    k_wconv<<<wgrid, 256, 0, stream>>>(W0, Wt);
    k_wconv<<<wgrid, 256, 0, stream>>>(W1, Wt + wsz);
    k_wconv<<<wgrid, 256, 0, stream>>>(W2, Wt + 2 * wsz);

    const float* bs[3] = {b0, b1, b2};
    const u16* h_in[3]  = {hB, hA, hB};
    u16*       h_out[3] = {hA, hB, hA};
    for (int l = 0; l < 3; l++) {
        k_aggregate<<<(N_NODESC + 3) / 4, 256, 0, stream>>>(
            h_in[l], row_off, csr_src, G);
        k_gemm<<<N_PAD / 64, 256, 0, stream>>>(
            G, Wt + (size_t)l * wsz, amp, att, bs[l], h_out[l]);
    }
    k_pool<<<4 * N_GRAPHSC, 256, 0, stream>>>(h_out[2], goff, pooled);
    k_bn_fc<<<1, 256, 0, stream>>>(pooled, gamma, beta, fcW, fcb, out);
}